// Round 10
// baseline (1008.001 us; speedup 1.0000x reference)
//
#include <hip/hip_runtime.h>
#include <hip/hip_bf16.h>
#include <math.h>

#define N_NODES 65536
#define N_EDGES 524288
#define N_GRAPHS 1024
#define NPG 64
#define FD 78
#define RPS 65600   // row_ptr stride (ints) per branch
#define BCAP 3072   // per-bucket edge capacity (mean 2048, >20 sigma)

typedef __attribute__((ext_vector_type(8))) short bf16x8;
typedef __attribute__((ext_vector_type(4))) float f32x4;

__device__ __forceinline__ unsigned short f2bf(float v) {
    unsigned int u = __float_as_uint(v);
    unsigned int r = (u + 0x7FFFu + ((u >> 16) & 1u)) >> 16;
    return (unsigned short)r;
}
__device__ __forceinline__ float bf2f(unsigned short h) {
    return __uint_as_float(((unsigned int)h) << 16);
}

// ---------------- split-bf16 MFMA GEMM, reg-prefetch pipelined ----------------
// omode 0: f32 to Cf; omode 1: hi/lo bf16 to Ch/Cl; omode 2: fused 64-row max-pool.
__global__ __launch_bounds__(256, 3) void gemm_mfma(
    const unsigned short* __restrict__ Ah, const unsigned short* __restrict__ Al,
    const unsigned short* __restrict__ Wh, const unsigned short* __restrict__ Wl,
    const float* __restrict__ bias,
    float* __restrict__ Cf, unsigned short* __restrict__ Ch, unsigned short* __restrict__ Cl,
    int N, int Kp, int ldc, int relu, int zpad, int omode)
{
    __shared__ __align__(16) unsigned short sAh[128][40];
    __shared__ __align__(16) unsigned short sAl[128][40];
    __shared__ __align__(16) unsigned short sBh[128][40];
    __shared__ __align__(16) unsigned short sBl[128][40];

    int tid = threadIdx.x;
    int bm = blockIdx.y << 7;
    int bn = blockIdx.x << 7;
    int lane = tid & 63;
    int wid = tid >> 6;
    int wr = wid >> 1, wc = wid & 1;
    int cr = lane & 15;
    int kg = lane >> 4;

    int r0 = tid >> 2;
    int sg = (tid & 3) * 8;
    const unsigned short* pAh = Ah + (size_t)(bm + r0) * Kp + sg;
    const unsigned short* pAl = Al + (size_t)(bm + r0) * Kp + sg;
    const unsigned short* pBh = Wh + (size_t)(bn + r0) * Kp + sg;
    const unsigned short* pBl = Wl + (size_t)(bn + r0) * Kp + sg;
    size_t rstep = (size_t)64 * Kp;

    uint4 vAh0, vAh1, vAl0, vAl1, vBh0, vBh1, vBl0, vBl1;
    auto LOADT = [&](int k0) {
        vAh0 = *(const uint4*)(pAh + k0);
        vAh1 = *(const uint4*)(pAh + k0 + rstep);
        vAl0 = *(const uint4*)(pAl + k0);
        vAl1 = *(const uint4*)(pAl + k0 + rstep);
        vBh0 = *(const uint4*)(pBh + k0);
        vBh1 = *(const uint4*)(pBh + k0 + rstep);
        vBl0 = *(const uint4*)(pBl + k0);
        vBl1 = *(const uint4*)(pBl + k0 + rstep);
    };
    auto WRITET = [&]() {
        *(uint4*)&sAh[r0][sg] = vAh0;
        *(uint4*)&sAh[r0 + 64][sg] = vAh1;
        *(uint4*)&sAl[r0][sg] = vAl0;
        *(uint4*)&sAl[r0 + 64][sg] = vAl1;
        *(uint4*)&sBh[r0][sg] = vBh0;
        *(uint4*)&sBh[r0 + 64][sg] = vBh1;
        *(uint4*)&sBl[r0][sg] = vBl0;
        *(uint4*)&sBl[r0 + 64][sg] = vBl1;
    };

    f32x4 acc[4][4] = {};

    LOADT(0);
    WRITET();
    __syncthreads();

    for (int k0 = 0; k0 < Kp; k0 += 32) {
        int more = (k0 + 32) < Kp;
        if (more) LOADT(k0 + 32);

        bf16x8 bH[4], bL[4];
        #pragma unroll
        for (int nf = 0; nf < 4; ++nf) {
            bH[nf] = *(const bf16x8*)&sBh[wc * 64 + nf * 16 + cr][kg * 8];
            bL[nf] = *(const bf16x8*)&sBl[wc * 64 + nf * 16 + cr][kg * 8];
        }
        #pragma unroll
        for (int mf = 0; mf < 4; ++mf) {
            bf16x8 aH = *(const bf16x8*)&sAh[wr * 64 + mf * 16 + cr][kg * 8];
            bf16x8 aL = *(const bf16x8*)&sAl[wr * 64 + mf * 16 + cr][kg * 8];
            #pragma unroll
            for (int nf = 0; nf < 4; ++nf) {
                acc[mf][nf] = __builtin_amdgcn_mfma_f32_16x16x32_bf16(aH, bH[nf], acc[mf][nf], 0, 0, 0);
                acc[mf][nf] = __builtin_amdgcn_mfma_f32_16x16x32_bf16(aH, bL[nf], acc[mf][nf], 0, 0, 0);
                acc[mf][nf] = __builtin_amdgcn_mfma_f32_16x16x32_bf16(aL, bH[nf], acc[mf][nf], 0, 0, 0);
            }
        }
        __syncthreads();
        if (more) {
            WRITET();
            __syncthreads();
        }
    }

    if (omode == 2) {
        int g = (blockIdx.y << 1) + wr;
        #pragma unroll
        for (int nf = 0; nf < 4; ++nf) {
            int col = bn + wc * 64 + nf * 16 + cr;
            if (col < N) {
                float m = -INFINITY;
                #pragma unroll
                for (int mf = 0; mf < 4; ++mf) {
                    f32x4 v = acc[mf][nf];
                    #pragma unroll
                    for (int j = 0; j < 4; ++j) m = fmaxf(m, v[j]);
                }
                m = fmaxf(m + bias[col], 0.f);
                m = fmaxf(m, __shfl_xor(m, 16, 64));
                m = fmaxf(m, __shfl_xor(m, 32, 64));
                if (kg == 0)
                    atomicMax((unsigned int*)&Cf[(size_t)g * ldc + col], __float_as_uint(m));
            }
        }
        return;
    }

    #pragma unroll
    for (int mf = 0; mf < 4; ++mf) {
        int rowbase = bm + wr * 64 + mf * 16 + kg * 4;
        #pragma unroll
        for (int nf = 0; nf < 4; ++nf) {
            int col = bn + wc * 64 + nf * 16 + cr;
            if (col >= ldc) continue;
            int live = col < N;
            if (!live && !zpad) continue;
            float bv = live ? bias[col] : 0.f;
            f32x4 v = acc[mf][nf];
            #pragma unroll
            for (int j = 0; j < 4; ++j) {
                size_t idx = (size_t)(rowbase + j) * ldc + col;
                float o = v[j] + bv;
                if (relu) o = fmaxf(o, 0.f);
                if (!live) o = 0.f;
                if (omode == 0) {
                    Cf[idx] = o;
                } else {
                    unsigned short h = f2bf(o);
                    Ch[idx] = h;
                    Cl[idx] = f2bf(o - bf2f(h));
                }
            }
        }
    }
}

// ---------------- split-K MFMA GEMM for skinny FCs ----------------
__global__ __launch_bounds__(256) void gemm_mfma_sk(
    const unsigned short* __restrict__ Ah, const unsigned short* __restrict__ Al,
    const unsigned short* __restrict__ Wh, const unsigned short* __restrict__ Wl,
    const float* __restrict__ bias, float* __restrict__ C,
    int Kp, int ldc, int kchunk)
{
    __shared__ __align__(16) unsigned short sAh[128][40];
    __shared__ __align__(16) unsigned short sAl[128][40];
    __shared__ __align__(16) unsigned short sBh[64][40];
    __shared__ __align__(16) unsigned short sBl[64][40];

    int tid = threadIdx.x;
    int bm = blockIdx.y << 7;
    int bn = blockIdx.x << 6;
    int kbase = blockIdx.z * kchunk;
    int lane = tid & 63;
    int wid = tid >> 6;
    int wr = wid >> 1, wc = wid & 1;
    int cr = lane & 15;
    int kg = lane >> 4;

    f32x4 acc[4][2] = {};

    for (int k0 = kbase; k0 < kbase + kchunk; k0 += 32) {
        #pragma unroll
        for (int s = tid; s < 512; s += 256) {
            int r = s >> 2, seg = s & 3;
            *(uint4*)&sAh[r][seg * 8] =
                *(const uint4*)(Ah + (size_t)(bm + r) * Kp + k0 + seg * 8);
        }
        #pragma unroll
        for (int s = tid; s < 512; s += 256) {
            int r = s >> 2, seg = s & 3;
            *(uint4*)&sAl[r][seg * 8] =
                *(const uint4*)(Al + (size_t)(bm + r) * Kp + k0 + seg * 8);
        }
        {
            int r = tid >> 2, seg = tid & 3;
            *(uint4*)&sBh[r][seg * 8] =
                *(const uint4*)(Wh + (size_t)(bn + r) * Kp + k0 + seg * 8);
            *(uint4*)&sBl[r][seg * 8] =
                *(const uint4*)(Wl + (size_t)(bn + r) * Kp + k0 + seg * 8);
        }
        __syncthreads();

        bf16x8 bH[2], bL[2];
        #pragma unroll
        for (int nf = 0; nf < 2; ++nf) {
            bH[nf] = *(const bf16x8*)&sBh[wc * 32 + nf * 16 + cr][kg * 8];
            bL[nf] = *(const bf16x8*)&sBl[wc * 32 + nf * 16 + cr][kg * 8];
        }
        #pragma unroll
        for (int mf = 0; mf < 4; ++mf) {
            bf16x8 aH = *(const bf16x8*)&sAh[wr * 64 + mf * 16 + cr][kg * 8];
            bf16x8 aL = *(const bf16x8*)&sAl[wr * 64 + mf * 16 + cr][kg * 8];
            #pragma unroll
            for (int nf = 0; nf < 2; ++nf) {
                acc[mf][nf] = __builtin_amdgcn_mfma_f32_16x16x32_bf16(aH, bH[nf], acc[mf][nf], 0, 0, 0);
                acc[mf][nf] = __builtin_amdgcn_mfma_f32_16x16x32_bf16(aH, bL[nf], acc[mf][nf], 0, 0, 0);
                acc[mf][nf] = __builtin_amdgcn_mfma_f32_16x16x32_bf16(aL, bH[nf], acc[mf][nf], 0, 0, 0);
            }
        }
        __syncthreads();
    }

    int z0 = blockIdx.z == 0;
    #pragma unroll
    for (int mf = 0; mf < 4; ++mf) {
        int rowbase = bm + wr * 64 + mf * 16 + kg * 4;
        #pragma unroll
        for (int nf = 0; nf < 2; ++nf) {
            int col = bn + wc * 32 + nf * 16 + cr;
            float bv = z0 ? bias[col] : 0.f;
            f32x4 v = acc[mf][nf];
            #pragma unroll
            for (int j = 0; j < 4; ++j)
                atomicAdd(&C[(size_t)(rowbase + j) * ldc + col], v[j] + bv);
        }
    }
}

// ---------------- batched weight prep ----------------
struct PrepDesc { const float* W; unsigned short* Wh; unsigned short* Wl; int K, N, Kp, Np; };
struct PrepArgs { PrepDesc d[11]; };

__global__ void prep_all(PrepArgs pa) {
    PrepDesc de = pa.d[blockIdx.y];
    int tot = de.Np * de.Kp;
    for (int t = blockIdx.x * blockDim.x + threadIdx.x; t < tot; t += gridDim.x * blockDim.x) {
        int n = t / de.Kp, k = t - n * de.Kp;
        float v = (n < de.N && k < de.K) ? de.W[(size_t)k * de.N + n] : 0.f;
        unsigned short h = f2bf(v);
        de.Wh[t] = h;
        de.Wl[t] = f2bf(v - bf2f(h));
    }
}

// ---------------- f32 [M,F] -> hi/lo split, zero-padded to Kp ----------------
__global__ void split_pad(const float* __restrict__ x, unsigned short* __restrict__ Xh,
                          unsigned short* __restrict__ Xl, int M, int F, int Kp) {
    int t = blockIdx.x * blockDim.x + threadIdx.x;
    if (t >= M * Kp) return;
    int i = t / Kp, c = t - i * Kp;
    float v = (c < F) ? x[(size_t)i * F + c] : 0.f;
    unsigned short h = f2bf(v);
    Xh[t] = h;
    Xl[t] = f2bf(v - bf2f(h));
}

// ---------------- small-M FC ----------------
__global__ __launch_bounds__(256) void fc_row(
    const float* __restrict__ A, const float* __restrict__ B,
    const float* __restrict__ bias, float* __restrict__ C,
    int M, int N, int K, int lda, int ldc, int relu)
{
    int nchunks = (N + 63) >> 6;
    int bid = blockIdx.x;
    int nc = bid % nchunks;
    int m = ((bid / nchunks) << 2) + (threadIdx.x >> 6);
    int lane = threadIdx.x & 63;
    if (m >= M) return;
    int n = (nc << 6) + lane;
    int nclamp = n < N ? n : N - 1;
    const float* __restrict__ a = A + (size_t)m * lda;
    const float* __restrict__ bp = B + nclamp;
    float acc = 0.f;
    int kk = 0;
    #pragma unroll 4
    for (; kk + 4 <= K; kk += 4) {
        float a0 = a[kk + 0], a1 = a[kk + 1], a2 = a[kk + 2], a3 = a[kk + 3];
        float b0 = bp[(size_t)(kk + 0) * N];
        float b1 = bp[(size_t)(kk + 1) * N];
        float b2 = bp[(size_t)(kk + 2) * N];
        float b3 = bp[(size_t)(kk + 3) * N];
        acc = fmaf(a0, b0, acc);
        acc = fmaf(a1, b1, acc);
        acc = fmaf(a2, b2, acc);
        acc = fmaf(a3, b3, acc);
    }
    for (; kk < K; ++kk)
        acc = fmaf(a[kk], bp[(size_t)kk * N], acc);
    if (n < N) {
        float v = acc + bias[n];
        if (relu) v = fmaxf(v, 0.f);
        C[(size_t)m * ldc + n] = v;
    }
}

// ---------------- bucketed CSR build ----------------
// Pass A: scatter packed edges (src<<8 | dst&255) into 512 buckets (branch<<8 | dst>>8)
__global__ void bucket_scatter(const int* __restrict__ s1, const int* __restrict__ d1,
                               const int* __restrict__ s2, const int* __restrict__ d2,
                               int* __restrict__ bcnt, unsigned int* __restrict__ bbuf, int E) {
    int t = blockIdx.x * blockDim.x + threadIdx.x;
    if (t >= 2 * E) return;
    int b = t >= E;
    int e = t - b * E;
    int s = b ? s2[e] : s1[e];
    int d = b ? d2[e] : d1[e];
    int bk = (b << 8) | (d >> 8);
    int pos = atomicAdd(&bcnt[bk], 1);
    if (pos < BCAP) bbuf[(size_t)bk * BCAP + pos] = ((unsigned int)s << 8) | (unsigned int)(d & 255);
}

// Pass B1: per-bucket per-node degree counts (LDS), coalesced write to cntB
__global__ __launch_bounds__(256) void bucket_count(const int* __restrict__ bcnt,
                                                    const unsigned int* __restrict__ bbuf,
                                                    int* __restrict__ cntB) {
    __shared__ int lc[256];
    int bk = blockIdx.x;
    lc[threadIdx.x] = 0;
    __syncthreads();
    int n = bcnt[bk]; if (n > BCAP) n = BCAP;
    const unsigned int* p = bbuf + (size_t)bk * BCAP;
    for (int i = threadIdx.x; i < n; i += 256)
        atomicAdd(&lc[p[i] & 255u], 1);
    __syncthreads();
    int br = bk >> 8, nb = (bk & 255) << 8;
    cntB[br * N_NODES + nb + threadIdx.x] = lc[threadIdx.x];
}

// Pass B2: per-bucket counting sort -> CSR slab (contiguous ~8KB write region)
__global__ __launch_bounds__(256) void bucket_sort(const int* __restrict__ bcnt,
                                                   const unsigned int* __restrict__ bbuf,
                                                   const int* __restrict__ rowpB,
                                                   int* __restrict__ csrsB) {
    __shared__ int lrow[256];
    __shared__ int lcur[256];
    int bk = blockIdx.x;
    int br = bk >> 8, nb = (bk & 255) << 8;
    lrow[threadIdx.x] = rowpB[br * RPS + nb + threadIdx.x];
    lcur[threadIdx.x] = 0;
    __syncthreads();
    int n = bcnt[bk]; if (n > BCAP) n = BCAP;
    const unsigned int* p = bbuf + (size_t)bk * BCAP;
    int* outp = csrsB + (size_t)br * N_EDGES;
    for (int i = threadIdx.x; i < n; i += 256) {
        unsigned int e = p[i];
        int dl = e & 255u;
        int pos = lrow[dl] + atomicAdd(&lcur[dl], 1);
        outp[pos] = (int)(e >> 8);
    }
}

__global__ void make_dinv2(const int* __restrict__ cnt, float* __restrict__ dinv) {
    int t = blockIdx.x * blockDim.x + threadIdx.x;
    if (t < 2 * N_NODES) dinv[t] = rsqrtf((float)cnt[t] + 1.0f);
}

// grid.x = 2 (one block per branch)
__global__ __launch_bounds__(1024) void scan_rowptr(const int* __restrict__ cntB,
                                                    int* __restrict__ rowpB) {
    __shared__ int sums[1024];
    const int* cnt = cntB + blockIdx.x * N_NODES;
    int* row_ptr = rowpB + blockIdx.x * RPS;
    int t = threadIdx.x;
    int base = t * 64;
    int s = 0;
    #pragma unroll 4
    for (int i = 0; i < 64; ++i) s += cnt[base + i];
    sums[t] = s;
    __syncthreads();
    for (int off = 1; off < 1024; off <<= 1) {
        int v = sums[t];
        int add = (t >= off) ? sums[t - off] : 0;
        __syncthreads();
        sums[t] = v + add;
        __syncthreads();
    }
    int run = (t == 0) ? 0 : sums[t - 1];
    for (int i = 0; i < 64; ++i) {
        row_ptr[base + i] = run;
        run += cnt[base + i];
    }
    if (t == 1023) row_ptr[N_NODES] = run;
}

// pad-repack: x[N,F] -> xp[N,S]
__global__ void repack_pad(const float* __restrict__ x, float* __restrict__ xp,
                           int F, int S) {
    int t = blockIdx.x * blockDim.x + threadIdx.x;
    int total = N_NODES * S;
    if (t >= total) return;
    int i = t / S, c = t - i * S;
    xp[t] = (c < F) ? x[(size_t)i * F + c] : 0.f;
}

// gather + normalize + split, 8 features/thread, float4 loads, edge loop x4
__global__ __launch_bounds__(256) void gather8(
    const float* __restrict__ x, const int* __restrict__ rowp,
    const int* __restrict__ csrs, const float* __restrict__ dinv,
    unsigned short* __restrict__ Ah, unsigned short* __restrict__ Al,
    int S, int Kp)
{
    int Kp8 = Kp >> 3;
    int t = blockIdx.x * blockDim.x + threadIdx.x;
    int total = N_NODES * Kp8;
    if (t >= total) return;
    int i = t / Kp8;
    int g = t - i * Kp8;
    int f = g << 3;
    size_t ob = (size_t)i * Kp + f;
    if (f >= S) {
        bf16x8 z = {};
        *(bf16x8*)&Ah[ob] = z;
        *(bf16x8*)&Al[ob] = z;
        return;
    }
    float di = dinv[i];
    const float* xr = x + (size_t)i * S + f;
    f32x4 s0 = *(const f32x4*)xr;
    f32x4 s1 = *(const f32x4*)(xr + 4);
    float w = di * di;
    s0 *= w;
    s1 *= w;
    int p0 = rowp[i], p1 = rowp[i + 1];
    int p = p0;
    for (; p + 4 <= p1; p += 4) {
        int sa = csrs[p], sb = csrs[p + 1], sc = csrs[p + 2], sd = csrs[p + 3];
        float ca = dinv[sa] * di, cb = dinv[sb] * di;
        float cc = dinv[sc] * di, cd = dinv[sd] * di;
        const float* ra = x + (size_t)sa * S + f;
        const float* rb = x + (size_t)sb * S + f;
        const float* rc = x + (size_t)sc * S + f;
        const float* rd = x + (size_t)sd * S + f;
        f32x4 a0 = *(const f32x4*)ra, a1 = *(const f32x4*)(ra + 4);
        f32x4 b0 = *(const f32x4*)rb, b1 = *(const f32x4*)(rb + 4);
        f32x4 c0 = *(const f32x4*)rc, c1 = *(const f32x4*)(rc + 4);
        f32x4 d0 = *(const f32x4*)rd, d1 = *(const f32x4*)(rd + 4);
        s0 += ca * a0 + cb * b0 + cc * c0 + cd * d0;
        s1 += ca * a1 + cb * b1 + cc * c1 + cd * d1;
    }
    for (; p < p1; ++p) {
        int sa = csrs[p];
        float ca = dinv[sa] * di;
        const float* ra = x + (size_t)sa * S + f;
        s0 += ca * *(const f32x4*)ra;
        s1 += ca * *(const f32x4*)(ra + 4);
    }
    bf16x8 hh, ll;
    #pragma unroll
    for (int j = 0; j < 4; ++j) {
        unsigned short h0 = f2bf(s0[j]);
        hh[j] = (short)h0;
        ll[j] = (short)f2bf(s0[j] - bf2f(h0));
        unsigned short h1 = f2bf(s1[j]);
        hh[4 + j] = (short)h1;
        ll[4 + j] = (short)f2bf(s1[j] - bf2f(h1));
    }
    *(bf16x8*)&Ah[ob] = hh;
    *(bf16x8*)&Al[ob] = ll;
}

// ---------------- host side ----------------
static inline void fc_launch(const float* A, const float* B, const float* bias, float* C,
                             int M, int N, int K, int lda, int ldc, int relu, hipStream_t s) {
    int nchunks = (N + 63) / 64;
    int mblocks = (M + 3) / 4;
    fc_row<<<nchunks * mblocks, 256, 0, s>>>(A, B, bias, C, M, N, K, lda, ldc, relu);
}

extern "C" void kernel_launch(void* const* d_in, const int* in_sizes, int n_in,
                              void* d_out, int out_size, void* d_ws, size_t ws_size,
                              hipStream_t stream) {
    (void)in_sizes; (void)n_in; (void)out_size; (void)ws_size;

    const float* x1     = (const float*)d_in[0];
    const int*   ei1    = (const int*)d_in[1];
    const float* x2     = (const float*)d_in[3];
    const int*   ei2    = (const int*)d_in[4];
    const float* target = (const float*)d_in[6];

    const float* xt_w  = (const float*)d_in[27];
    const float* xt_b  = (const float*)d_in[28];
    const float* fc1_w = (const float*)d_in[29];
    const float* fc1_b = (const float*)d_in[30];
    const float* fc2_w = (const float*)d_in[31];
    const float* fc2_b = (const float*)d_in[32];
    const float* out_w = (const float*)d_in[33];
    const float* out_b = (const float*)d_in[34];

    char* ws = (char*)d_ws;
    unsigned short* Ahb = (unsigned short*)(ws + 0);           // 20,971,520
    unsigned short* Alb = (unsigned short*)(ws + 20971520);    // 20,971,520
    float* Y3   = (float*)(ws + 41943040);    // 81,788,928 (xpad/y1)
    char*  S2   = ws + 123731968;             // 41,943,040 (y2; then fc scratch)
    int*   csrsB = (int*) (ws + 165675008);   // 2 x 2,097,152
    int*   rowpB = (int*) (ws + 169869312);   // 2 x 262,400
    int*   cntB  = (int*) (ws + 170394112);   // 2 x 262,144
    float* dinvB = (float*)(ws + 170918400);  // 2 x 262,144
    float* xc   = (float*)(ws + 171442688);   // 1,048,576
    float* xc1  = (float*)(ws + 172491264);   // 524,288
    float* xc2  = (float*)(ws + 173015552);   // 131,072
    unsigned short* wt    = (unsigned short*)(ws + 173146624); // conv weights 786,432 B
    unsigned short* wtfc1 = (unsigned short*)(ws + 173933056); // 2 x 1,310,720 B
    unsigned short* wtfc2 = (unsigned short*)(ws + 176554496); // 2 x 524,288 B
    unsigned short* wtxt  = (unsigned short*)(ws + 177603072); // 524,288 B
    // total ws use: 178,127,360 B

    // CSR-build scratch aliases Ahb/Alb (dead until convs start)
    unsigned int* bbuf = (unsigned int*)Ahb;   // 512*3072*4 = 6,291,456 B
    int*          bcnt = (int*)Alb;            // 2048 B

    float* xpad = Y3;
    float* y1   = Y3;
    float* y2   = (float*)S2;
    unsigned short* Ph = (unsigned short*)(S2 + 0);
    unsigned short* Pl = (unsigned short*)(S2 + 655360);
    unsigned short* Fh = (unsigned short*)(S2 + 1310720);
    unsigned short* Fl = (unsigned short*)(S2 + 3407872);
    unsigned short* Th = (unsigned short*)(S2 + 5505024);
    unsigned short* Tl = (unsigned short*)(S2 + 7602176);
    float* pooled = (float*)(S2 + 9699328);

    const int E = N_EDGES;

    const int Ks[3]  = { FD, FD, FD * 2 };
    const int Ns[3]  = { FD, FD * 2, FD * 4 };
    const int Kps[3] = { 96, 96, 160 };
    const int Nps[3] = { 128, 256, 384 };
    const int Ss[3]  = { 80, 80, 160 };
    const int Ldc[3] = { 80, 160, 312 };
    const int wtoff[3] = { 0, 24576, 73728 };
    const int WT_BRANCH = 196608;

    // ---- batched weight prep (1 launch) ----
    PrepArgs pa;
    for (int br = 0; br < 2; ++br) {
        int base = 7 + br * 10;
        for (int c = 0; c < 3; ++c) {
            unsigned short* wh = wt + br * WT_BRANCH + wtoff[c];
            pa.d[br * 3 + c] = { (const float*)d_in[base + 2 * c], wh,
                                 wh + Nps[c] * Kps[c], Ks[c], Ns[c], Kps[c], Nps[c] };
        }
        pa.d[6 + br] = { (const float*)d_in[base + 6], wtfc1 + br * 655360,
                         wtfc1 + br * 655360 + 327680, FD * 4, 1024, 320, 1024 };
        pa.d[8 + br] = { (const float*)d_in[base + 8], wtfc2 + br * 262144,
                         wtfc2 + br * 262144 + 131072, 1024, 64, 1024, 128 };
    }
    pa.d[10] = { xt_w, wtxt, wtxt + 131072, 1000, 128, 1024, 128 };
    prep_all<<<dim3(256, 11), 256, 0, stream>>>(pa);

    // ---- bucketed CSR build, both branches ----
    const int* src1 = ei1, *dst1 = ei1 + E;
    const int* src2 = ei2, *dst2 = ei2 + E;
    hipMemsetAsync(bcnt, 0, 512 * sizeof(int), stream);
    bucket_scatter<<<(2 * E + 255) / 256, 256, 0, stream>>>(src1, dst1, src2, dst2, bcnt, bbuf, E);
    bucket_count<<<512, 256, 0, stream>>>(bcnt, bbuf, cntB);
    make_dinv2<<<(2 * N_NODES + 255) / 256, 256, 0, stream>>>(cntB, dinvB);
    scan_rowptr<<<2, 1024, 0, stream>>>(cntB, rowpB);
    bucket_sort<<<512, 256, 0, stream>>>(bcnt, bbuf, rowpB, csrsB);

    // xc accumulated by split-K atomics -> zero it up front
    hipMemsetAsync(xc, 0, N_GRAPHS * 256 * sizeof(float), stream);

    for (int br = 0; br < 2; ++br) {
        const float* x = br == 0 ? x1 : x2;
        const int* rowp = rowpB + br * RPS;
        const int* csr  = csrsB + br * E;
        const float* dv = dinvB + br * N_NODES;
        int base = 7 + br * 10;
        const float* bias_c[3] = { (const float*)d_in[base + 1], (const float*)d_in[base + 3],
                                   (const float*)d_in[base + 5] };
        const float* bfc1b = (const float*)d_in[base + 7];
        const float* bfc2b = (const float*)d_in[base + 9];

        repack_pad<<<(N_NODES * 80 + 255) / 256, 256, 0, stream>>>(x, xpad, FD, 80);

        const float* cin[3]  = { xpad, y1, y2 };
        float*       cout[3] = { y1, y2, pooled };
        for (int c = 0; c < 3; ++c) {
            int Kp = Kps[c], Np = Nps[c], S = Ss[c];
            int total = N_NODES * (Kp >> 3);
            gather8<<<(total + 255) / 256, 256, 0, stream>>>(
                cin[c], rowp, csr, dv, Ahb, Alb, S, Kp);
            if (c == 2) {
                hipMemsetAsync(pooled, 0, N_GRAPHS * 320 * sizeof(float), stream);
                gemm_mfma<<<dim3(Np / 128, 512), 256, 0, stream>>>(
                    Ahb, Alb, wt + br * WT_BRANCH + wtoff[c],
                    wt + br * WT_BRANCH + wtoff[c] + Np * Kp, bias_c[c],
                    pooled, nullptr, nullptr, Ns[c], Kp, 320, 1, 0, 2);
            } else {
                gemm_mfma<<<dim3(Np / 128, 512), 256, 0, stream>>>(
                    Ahb, Alb, wt + br * WT_BRANCH + wtoff[c],
                    wt + br * WT_BRANCH + wtoff[c] + Np * Kp, bias_c[c],
                    cout[c], nullptr, nullptr, Ns[c], Kp, Ldc[c], 1, 1, 0);
            }
        }

        // ---- branch MLP ----
        split_pad<<<(N_GRAPHS * 320 + 255) / 256, 256, 0, stream>>>(pooled, Ph, Pl, N_GRAPHS, 320, 320);
        gemm_mfma<<<dim3(8, 8), 256, 0, stream>>>(
            Ph, Pl, wtfc1 + br * 655360, wtfc1 + br * 655360 + 327680, bfc1b,
            nullptr, Fh, Fl, 1024, 320, 1024, 1, 1, 1);
        gemm_mfma_sk<<<dim3(1, 8, 8), 256, 0, stream>>>(
            Fh, Fl, wtfc2 + br * 262144, wtfc2 + br * 262144 + 131072, bfc2b,
            xc + br * 64, 1024, 256, 128);
    }

    // xt
    split_pad<<<(1024 * 1024 + 255) / 256, 256, 0, stream>>>(target, Th, Tl, 1024, 1000, 1024);
    gemm_mfma_sk<<<dim3(2, 8, 8), 256, 0, stream>>>(
        Th, Tl, wtxt, wtxt + 131072, xt_b,
        xc + 128, 1024, 256, 128);

    // head
    fc_launch(xc,  fc1_w, fc1_b, xc1, N_GRAPHS, 128, 256, 256, 128, 1, stream);
    fc_launch(xc1, fc2_w, fc2_b, xc2, N_GRAPHS, 32, 128, 128, 32, 1, stream);
    fc_launch(xc2, out_w, out_b, (float*)d_out, N_GRAPHS, 1, 32, 32, 1, 0, stream);
}

// Round 11
// 585.951 us; speedup vs baseline: 1.7203x; 1.7203x over previous
//
#include <hip/hip_runtime.h>
#include <hip/hip_bf16.h>
#include <math.h>

#define N_NODES 65536
#define N_EDGES 524288
#define N_GRAPHS 1024
#define NPG 64
#define FD 78
#define RPS 65600   // row_ptr stride (ints) per branch
#define BCAP 3072   // per-bucket edge capacity (mean 2048, >20 sigma)
#define EPB 4096    // edges per scatter block

typedef __attribute__((ext_vector_type(8))) short bf16x8;
typedef __attribute__((ext_vector_type(4))) float f32x4;

__device__ __forceinline__ unsigned short f2bf(float v) {
    unsigned int u = __float_as_uint(v);
    unsigned int r = (u + 0x7FFFu + ((u >> 16) & 1u)) >> 16;
    return (unsigned short)r;
}
__device__ __forceinline__ float bf2f(unsigned short h) {
    return __uint_as_float(((unsigned int)h) << 16);
}

// ---------------- split-bf16 MFMA GEMM, reg-prefetch pipelined ----------------
// omode 0: f32 to Cf; omode 1: hi/lo bf16 to Ch/Cl; omode 2: fused 64-row max-pool.
__global__ __launch_bounds__(256, 3) void gemm_mfma(
    const unsigned short* __restrict__ Ah, const unsigned short* __restrict__ Al,
    const unsigned short* __restrict__ Wh, const unsigned short* __restrict__ Wl,
    const float* __restrict__ bias,
    float* __restrict__ Cf, unsigned short* __restrict__ Ch, unsigned short* __restrict__ Cl,
    int N, int Kp, int ldc, int relu, int zpad, int omode)
{
    __shared__ __align__(16) unsigned short sAh[128][40];
    __shared__ __align__(16) unsigned short sAl[128][40];
    __shared__ __align__(16) unsigned short sBh[128][40];
    __shared__ __align__(16) unsigned short sBl[128][40];

    int tid = threadIdx.x;
    int bm = blockIdx.y << 7;
    int bn = blockIdx.x << 7;
    int lane = tid & 63;
    int wid = tid >> 6;
    int wr = wid >> 1, wc = wid & 1;
    int cr = lane & 15;
    int kg = lane >> 4;

    int r0 = tid >> 2;
    int sg = (tid & 3) * 8;
    const unsigned short* pAh = Ah + (size_t)(bm + r0) * Kp + sg;
    const unsigned short* pAl = Al + (size_t)(bm + r0) * Kp + sg;
    const unsigned short* pBh = Wh + (size_t)(bn + r0) * Kp + sg;
    const unsigned short* pBl = Wl + (size_t)(bn + r0) * Kp + sg;
    size_t rstep = (size_t)64 * Kp;

    uint4 vAh0, vAh1, vAl0, vAl1, vBh0, vBh1, vBl0, vBl1;
    auto LOADT = [&](int k0) {
        vAh0 = *(const uint4*)(pAh + k0);
        vAh1 = *(const uint4*)(pAh + k0 + rstep);
        vAl0 = *(const uint4*)(pAl + k0);
        vAl1 = *(const uint4*)(pAl + k0 + rstep);
        vBh0 = *(const uint4*)(pBh + k0);
        vBh1 = *(const uint4*)(pBh + k0 + rstep);
        vBl0 = *(const uint4*)(pBl + k0);
        vBl1 = *(const uint4*)(pBl + k0 + rstep);
    };
    auto WRITET = [&]() {
        *(uint4*)&sAh[r0][sg] = vAh0;
        *(uint4*)&sAh[r0 + 64][sg] = vAh1;
        *(uint4*)&sAl[r0][sg] = vAl0;
        *(uint4*)&sAl[r0 + 64][sg] = vAl1;
        *(uint4*)&sBh[r0][sg] = vBh0;
        *(uint4*)&sBh[r0 + 64][sg] = vBh1;
        *(uint4*)&sBl[r0][sg] = vBl0;
        *(uint4*)&sBl[r0 + 64][sg] = vBl1;
    };

    f32x4 acc[4][4] = {};

    LOADT(0);
    WRITET();
    __syncthreads();

    for (int k0 = 0; k0 < Kp; k0 += 32) {
        int more = (k0 + 32) < Kp;
        if (more) LOADT(k0 + 32);

        bf16x8 bH[4], bL[4];
        #pragma unroll
        for (int nf = 0; nf < 4; ++nf) {
            bH[nf] = *(const bf16x8*)&sBh[wc * 64 + nf * 16 + cr][kg * 8];
            bL[nf] = *(const bf16x8*)&sBl[wc * 64 + nf * 16 + cr][kg * 8];
        }
        #pragma unroll
        for (int mf = 0; mf < 4; ++mf) {
            bf16x8 aH = *(const bf16x8*)&sAh[wr * 64 + mf * 16 + cr][kg * 8];
            bf16x8 aL = *(const bf16x8*)&sAl[wr * 64 + mf * 16 + cr][kg * 8];
            #pragma unroll
            for (int nf = 0; nf < 4; ++nf) {
                acc[mf][nf] = __builtin_amdgcn_mfma_f32_16x16x32_bf16(aH, bH[nf], acc[mf][nf], 0, 0, 0);
                acc[mf][nf] = __builtin_amdgcn_mfma_f32_16x16x32_bf16(aH, bL[nf], acc[mf][nf], 0, 0, 0);
                acc[mf][nf] = __builtin_amdgcn_mfma_f32_16x16x32_bf16(aL, bH[nf], acc[mf][nf], 0, 0, 0);
            }
        }
        __syncthreads();
        if (more) {
            WRITET();
            __syncthreads();
        }
    }

    if (omode == 2) {
        int g = (blockIdx.y << 1) + wr;
        #pragma unroll
        for (int nf = 0; nf < 4; ++nf) {
            int col = bn + wc * 64 + nf * 16 + cr;
            if (col < N) {
                float m = -INFINITY;
                #pragma unroll
                for (int mf = 0; mf < 4; ++mf) {
                    f32x4 v = acc[mf][nf];
                    #pragma unroll
                    for (int j = 0; j < 4; ++j) m = fmaxf(m, v[j]);
                }
                m = fmaxf(m + bias[col], 0.f);
                m = fmaxf(m, __shfl_xor(m, 16, 64));
                m = fmaxf(m, __shfl_xor(m, 32, 64));
                if (kg == 0)
                    atomicMax((unsigned int*)&Cf[(size_t)g * ldc + col], __float_as_uint(m));
            }
        }
        return;
    }

    #pragma unroll
    for (int mf = 0; mf < 4; ++mf) {
        int rowbase = bm + wr * 64 + mf * 16 + kg * 4;
        #pragma unroll
        for (int nf = 0; nf < 4; ++nf) {
            int col = bn + wc * 64 + nf * 16 + cr;
            if (col >= ldc) continue;
            int live = col < N;
            if (!live && !zpad) continue;
            float bv = live ? bias[col] : 0.f;
            f32x4 v = acc[mf][nf];
            #pragma unroll
            for (int j = 0; j < 4; ++j) {
                size_t idx = (size_t)(rowbase + j) * ldc + col;
                float o = v[j] + bv;
                if (relu) o = fmaxf(o, 0.f);
                if (!live) o = 0.f;
                if (omode == 0) {
                    Cf[idx] = o;
                } else {
                    unsigned short h = f2bf(o);
                    Ch[idx] = h;
                    Cl[idx] = f2bf(o - bf2f(h));
                }
            }
        }
    }
}

// ---------------- split-K MFMA GEMM for skinny FCs ----------------
__global__ __launch_bounds__(256) void gemm_mfma_sk(
    const unsigned short* __restrict__ Ah, const unsigned short* __restrict__ Al,
    const unsigned short* __restrict__ Wh, const unsigned short* __restrict__ Wl,
    const float* __restrict__ bias, float* __restrict__ C,
    int Kp, int ldc, int kchunk)
{
    __shared__ __align__(16) unsigned short sAh[128][40];
    __shared__ __align__(16) unsigned short sAl[128][40];
    __shared__ __align__(16) unsigned short sBh[64][40];
    __shared__ __align__(16) unsigned short sBl[64][40];

    int tid = threadIdx.x;
    int bm = blockIdx.y << 7;
    int bn = blockIdx.x << 6;
    int kbase = blockIdx.z * kchunk;
    int lane = tid & 63;
    int wid = tid >> 6;
    int wr = wid >> 1, wc = wid & 1;
    int cr = lane & 15;
    int kg = lane >> 4;

    f32x4 acc[4][2] = {};

    for (int k0 = kbase; k0 < kbase + kchunk; k0 += 32) {
        #pragma unroll
        for (int s = tid; s < 512; s += 256) {
            int r = s >> 2, seg = s & 3;
            *(uint4*)&sAh[r][seg * 8] =
                *(const uint4*)(Ah + (size_t)(bm + r) * Kp + k0 + seg * 8);
        }
        #pragma unroll
        for (int s = tid; s < 512; s += 256) {
            int r = s >> 2, seg = s & 3;
            *(uint4*)&sAl[r][seg * 8] =
                *(const uint4*)(Al + (size_t)(bm + r) * Kp + k0 + seg * 8);
        }
        {
            int r = tid >> 2, seg = tid & 3;
            *(uint4*)&sBh[r][seg * 8] =
                *(const uint4*)(Wh + (size_t)(bn + r) * Kp + k0 + seg * 8);
            *(uint4*)&sBl[r][seg * 8] =
                *(const uint4*)(Wl + (size_t)(bn + r) * Kp + k0 + seg * 8);
        }
        __syncthreads();

        bf16x8 bH[2], bL[2];
        #pragma unroll
        for (int nf = 0; nf < 2; ++nf) {
            bH[nf] = *(const bf16x8*)&sBh[wc * 32 + nf * 16 + cr][kg * 8];
            bL[nf] = *(const bf16x8*)&sBl[wc * 32 + nf * 16 + cr][kg * 8];
        }
        #pragma unroll
        for (int mf = 0; mf < 4; ++mf) {
            bf16x8 aH = *(const bf16x8*)&sAh[wr * 64 + mf * 16 + cr][kg * 8];
            bf16x8 aL = *(const bf16x8*)&sAl[wr * 64 + mf * 16 + cr][kg * 8];
            #pragma unroll
            for (int nf = 0; nf < 2; ++nf) {
                acc[mf][nf] = __builtin_amdgcn_mfma_f32_16x16x32_bf16(aH, bH[nf], acc[mf][nf], 0, 0, 0);
                acc[mf][nf] = __builtin_amdgcn_mfma_f32_16x16x32_bf16(aH, bL[nf], acc[mf][nf], 0, 0, 0);
                acc[mf][nf] = __builtin_amdgcn_mfma_f32_16x16x32_bf16(aL, bH[nf], acc[mf][nf], 0, 0, 0);
            }
        }
        __syncthreads();
    }

    int z0 = blockIdx.z == 0;
    #pragma unroll
    for (int mf = 0; mf < 4; ++mf) {
        int rowbase = bm + wr * 64 + mf * 16 + kg * 4;
        #pragma unroll
        for (int nf = 0; nf < 2; ++nf) {
            int col = bn + wc * 32 + nf * 16 + cr;
            float bv = z0 ? bias[col] : 0.f;
            f32x4 v = acc[mf][nf];
            #pragma unroll
            for (int j = 0; j < 4; ++j)
                atomicAdd(&C[(size_t)(rowbase + j) * ldc + col], v[j] + bv);
        }
    }
}

// ---------------- batched weight prep ----------------
struct PrepDesc { const float* W; unsigned short* Wh; unsigned short* Wl; int K, N, Kp, Np; };
struct PrepArgs { PrepDesc d[11]; };

__global__ void prep_all(PrepArgs pa) {
    PrepDesc de = pa.d[blockIdx.y];
    int tot = de.Np * de.Kp;
    for (int t = blockIdx.x * blockDim.x + threadIdx.x; t < tot; t += gridDim.x * blockDim.x) {
        int n = t / de.Kp, k = t - n * de.Kp;
        float v = (n < de.N && k < de.K) ? de.W[(size_t)k * de.N + n] : 0.f;
        unsigned short h = f2bf(v);
        de.Wh[t] = h;
        de.Wl[t] = f2bf(v - bf2f(h));
    }
}

// ---------------- f32 [M,F] -> hi/lo split, zero-padded to Kp ----------------
__global__ void split_pad(const float* __restrict__ x, unsigned short* __restrict__ Xh,
                          unsigned short* __restrict__ Xl, int M, int F, int Kp) {
    int t = blockIdx.x * blockDim.x + threadIdx.x;
    if (t >= M * Kp) return;
    int i = t / Kp, c = t - i * Kp;
    float v = (c < F) ? x[(size_t)i * F + c] : 0.f;
    unsigned short h = f2bf(v);
    Xh[t] = h;
    Xl[t] = f2bf(v - bf2f(h));
}

// ---------------- small-M FC ----------------
__global__ __launch_bounds__(256) void fc_row(
    const float* __restrict__ A, const float* __restrict__ B,
    const float* __restrict__ bias, float* __restrict__ C,
    int M, int N, int K, int lda, int ldc, int relu)
{
    int nchunks = (N + 63) >> 6;
    int bid = blockIdx.x;
    int nc = bid % nchunks;
    int m = ((bid / nchunks) << 2) + (threadIdx.x >> 6);
    int lane = threadIdx.x & 63;
    if (m >= M) return;
    int n = (nc << 6) + lane;
    int nclamp = n < N ? n : N - 1;
    const float* __restrict__ a = A + (size_t)m * lda;
    const float* __restrict__ bp = B + nclamp;
    float acc = 0.f;
    int kk = 0;
    #pragma unroll 4
    for (; kk + 4 <= K; kk += 4) {
        float a0 = a[kk + 0], a1 = a[kk + 1], a2 = a[kk + 2], a3 = a[kk + 3];
        float b0 = bp[(size_t)(kk + 0) * N];
        float b1 = bp[(size_t)(kk + 1) * N];
        float b2 = bp[(size_t)(kk + 2) * N];
        float b3 = bp[(size_t)(kk + 3) * N];
        acc = fmaf(a0, b0, acc);
        acc = fmaf(a1, b1, acc);
        acc = fmaf(a2, b2, acc);
        acc = fmaf(a3, b3, acc);
    }
    for (; kk < K; ++kk)
        acc = fmaf(a[kk], bp[(size_t)kk * N], acc);
    if (n < N) {
        float v = acc + bias[n];
        if (relu) v = fmaxf(v, 0.f);
        C[(size_t)m * ldc + n] = v;
    }
}

// ---------------- bucketed CSR build ----------------
// Pass A (two-level): each 1024-thr block owns EPB contiguous edges of ONE branch.
// Per-edge rank via LDS histogram atomics; ONE global atomicAdd per (block,bucket)
// to reserve slab space; then scatter writes land in contiguous per-block runs.
__global__ __launch_bounds__(1024) void bucket_scatter(
    const int* __restrict__ s1, const int* __restrict__ d1,
    const int* __restrict__ s2, const int* __restrict__ d2,
    int* __restrict__ bcnt, unsigned int* __restrict__ bbuf, int E)
{
    __shared__ int lhist[256];
    __shared__ int lbase[256];
    int nblk = E / EPB;                     // blocks per branch
    int b = blockIdx.x >= nblk;
    int blk = blockIdx.x - b * nblk;
    const int* sp = b ? s2 : s1;
    const int* dp = b ? d2 : d1;
    int e0 = blk * EPB;
    if (threadIdx.x < 256) lhist[threadIdx.x] = 0;
    __syncthreads();

    unsigned int pack[EPB / 1024];
    int bkt[EPB / 1024], rank[EPB / 1024];
    #pragma unroll
    for (int i = 0; i < EPB / 1024; ++i) {
        int e = e0 + threadIdx.x + i * 1024;
        int s = sp[e], d = dp[e];
        bkt[i] = d >> 8;
        pack[i] = ((unsigned int)s << 8) | (unsigned int)(d & 255);
        rank[i] = atomicAdd(&lhist[bkt[i]], 1);
    }
    __syncthreads();
    if (threadIdx.x < 256) {
        int c = lhist[threadIdx.x];
        lbase[threadIdx.x] = c ? atomicAdd(&bcnt[(b << 8) | threadIdx.x], c) : 0;
    }
    __syncthreads();
    #pragma unroll
    for (int i = 0; i < EPB / 1024; ++i) {
        int pos = lbase[bkt[i]] + rank[i];
        if (pos < BCAP)
            bbuf[(size_t)((b << 8) | bkt[i]) * BCAP + pos] = pack[i];
    }
}

// Pass B1: per-bucket per-node degree counts (LDS), coalesced write to cntB
__global__ __launch_bounds__(256) void bucket_count(const int* __restrict__ bcnt,
                                                    const unsigned int* __restrict__ bbuf,
                                                    int* __restrict__ cntB) {
    __shared__ int lc[256];
    int bk = blockIdx.x;
    lc[threadIdx.x] = 0;
    __syncthreads();
    int n = bcnt[bk]; if (n > BCAP) n = BCAP;
    const unsigned int* p = bbuf + (size_t)bk * BCAP;
    for (int i = threadIdx.x; i < n; i += 256)
        atomicAdd(&lc[p[i] & 255u], 1);
    __syncthreads();
    int br = bk >> 8, nb = (bk & 255) << 8;
    cntB[br * N_NODES + nb + threadIdx.x] = lc[threadIdx.x];
}

// Pass B2: per-bucket counting sort -> CSR slab
__global__ __launch_bounds__(256) void bucket_sort(const int* __restrict__ bcnt,
                                                   const unsigned int* __restrict__ bbuf,
                                                   const int* __restrict__ rowpB,
                                                   int* __restrict__ csrsB) {
    __shared__ int lrow[256];
    __shared__ int lcur[256];
    int bk = blockIdx.x;
    int br = bk >> 8, nb = (bk & 255) << 8;
    lrow[threadIdx.x] = rowpB[br * RPS + nb + threadIdx.x];
    lcur[threadIdx.x] = 0;
    __syncthreads();
    int n = bcnt[bk]; if (n > BCAP) n = BCAP;
    const unsigned int* p = bbuf + (size_t)bk * BCAP;
    int* outp = csrsB + (size_t)br * N_EDGES;
    for (int i = threadIdx.x; i < n; i += 256) {
        unsigned int e = p[i];
        int dl = e & 255u;
        int pos = lrow[dl] + atomicAdd(&lcur[dl], 1);
        outp[pos] = (int)(e >> 8);
    }
}

__global__ void make_dinv2(const int* __restrict__ cnt, float* __restrict__ dinv) {
    int t = blockIdx.x * blockDim.x + threadIdx.x;
    if (t < 2 * N_NODES) dinv[t] = rsqrtf((float)cnt[t] + 1.0f);
}

// grid.x = 2 (one block per branch)
__global__ __launch_bounds__(1024) void scan_rowptr(const int* __restrict__ cntB,
                                                    int* __restrict__ rowpB) {
    __shared__ int sums[1024];
    const int* cnt = cntB + blockIdx.x * N_NODES;
    int* row_ptr = rowpB + blockIdx.x * RPS;
    int t = threadIdx.x;
    int base = t * 64;
    int s = 0;
    #pragma unroll 4
    for (int i = 0; i < 64; ++i) s += cnt[base + i];
    sums[t] = s;
    __syncthreads();
    for (int off = 1; off < 1024; off <<= 1) {
        int v = sums[t];
        int add = (t >= off) ? sums[t - off] : 0;
        __syncthreads();
        sums[t] = v + add;
        __syncthreads();
    }
    int run = (t == 0) ? 0 : sums[t - 1];
    for (int i = 0; i < 64; ++i) {
        row_ptr[base + i] = run;
        run += cnt[base + i];
    }
    if (t == 1023) row_ptr[N_NODES] = run;
}

// pad-repack: x[N,F] -> xp[N,S]
__global__ void repack_pad(const float* __restrict__ x, float* __restrict__ xp,
                           int F, int S) {
    int t = blockIdx.x * blockDim.x + threadIdx.x;
    int total = N_NODES * S;
    if (t >= total) return;
    int i = t / S, c = t - i * S;
    xp[t] = (c < F) ? x[(size_t)i * F + c] : 0.f;
}

// gather + normalize + split, 8 features/thread, float4 loads, edge loop x4
__global__ __launch_bounds__(256) void gather8(
    const float* __restrict__ x, const int* __restrict__ rowp,
    const int* __restrict__ csrs, const float* __restrict__ dinv,
    unsigned short* __restrict__ Ah, unsigned short* __restrict__ Al,
    int S, int Kp)
{
    int Kp8 = Kp >> 3;
    int t = blockIdx.x * blockDim.x + threadIdx.x;
    int total = N_NODES * Kp8;
    if (t >= total) return;
    int i = t / Kp8;
    int g = t - i * Kp8;
    int f = g << 3;
    size_t ob = (size_t)i * Kp + f;
    if (f >= S) {
        bf16x8 z = {};
        *(bf16x8*)&Ah[ob] = z;
        *(bf16x8*)&Al[ob] = z;
        return;
    }
    float di = dinv[i];
    const float* xr = x + (size_t)i * S + f;
    f32x4 s0 = *(const f32x4*)xr;
    f32x4 s1 = *(const f32x4*)(xr + 4);
    float w = di * di;
    s0 *= w;
    s1 *= w;
    int p0 = rowp[i], p1 = rowp[i + 1];
    int p = p0;
    for (; p + 4 <= p1; p += 4) {
        int sa = csrs[p], sb = csrs[p + 1], sc = csrs[p + 2], sd = csrs[p + 3];
        float ca = dinv[sa] * di, cb = dinv[sb] * di;
        float cc = dinv[sc] * di, cd = dinv[sd] * di;
        const float* ra = x + (size_t)sa * S + f;
        const float* rb = x + (size_t)sb * S + f;
        const float* rc = x + (size_t)sc * S + f;
        const float* rd = x + (size_t)sd * S + f;
        f32x4 a0 = *(const f32x4*)ra, a1 = *(const f32x4*)(ra + 4);
        f32x4 b0 = *(const f32x4*)rb, b1 = *(const f32x4*)(rb + 4);
        f32x4 c0 = *(const f32x4*)rc, c1 = *(const f32x4*)(rc + 4);
        f32x4 d0 = *(const f32x4*)rd, d1 = *(const f32x4*)(rd + 4);
        s0 += ca * a0 + cb * b0 + cc * c0 + cd * d0;
        s1 += ca * a1 + cb * b1 + cc * c1 + cd * d1;
    }
    for (; p < p1; ++p) {
        int sa = csrs[p];
        float ca = dinv[sa] * di;
        const float* ra = x + (size_t)sa * S + f;
        s0 += ca * *(const f32x4*)ra;
        s1 += ca * *(const f32x4*)(ra + 4);
    }
    bf16x8 hh, ll;
    #pragma unroll
    for (int j = 0; j < 4; ++j) {
        unsigned short h0 = f2bf(s0[j]);
        hh[j] = (short)h0;
        ll[j] = (short)f2bf(s0[j] - bf2f(h0));
        unsigned short h1 = f2bf(s1[j]);
        hh[4 + j] = (short)h1;
        ll[4 + j] = (short)f2bf(s1[j] - bf2f(h1));
    }
    *(bf16x8*)&Ah[ob] = hh;
    *(bf16x8*)&Al[ob] = ll;
}

// ---------------- host side ----------------
static inline void fc_launch(const float* A, const float* B, const float* bias, float* C,
                             int M, int N, int K, int lda, int ldc, int relu, hipStream_t s) {
    int nchunks = (N + 63) / 64;
    int mblocks = (M + 3) / 4;
    fc_row<<<nchunks * mblocks, 256, 0, s>>>(A, B, bias, C, M, N, K, lda, ldc, relu);
}

extern "C" void kernel_launch(void* const* d_in, const int* in_sizes, int n_in,
                              void* d_out, int out_size, void* d_ws, size_t ws_size,
                              hipStream_t stream) {
    (void)in_sizes; (void)n_in; (void)out_size; (void)ws_size;

    const float* x1     = (const float*)d_in[0];
    const int*   ei1    = (const int*)d_in[1];
    const float* x2     = (const float*)d_in[3];
    const int*   ei2    = (const int*)d_in[4];
    const float* target = (const float*)d_in[6];

    const float* xt_w  = (const float*)d_in[27];
    const float* xt_b  = (const float*)d_in[28];
    const float* fc1_w = (const float*)d_in[29];
    const float* fc1_b = (const float*)d_in[30];
    const float* fc2_w = (const float*)d_in[31];
    const float* fc2_b = (const float*)d_in[32];
    const float* out_w = (const float*)d_in[33];
    const float* out_b = (const float*)d_in[34];

    char* ws = (char*)d_ws;
    unsigned short* Ahb = (unsigned short*)(ws + 0);           // 20,971,520
    unsigned short* Alb = (unsigned short*)(ws + 20971520);    // 20,971,520
    float* Y3   = (float*)(ws + 41943040);    // 81,788,928 (xpad/y1)
    char*  S2   = ws + 123731968;             // 41,943,040 (y2; then fc scratch)
    int*   csrsB = (int*) (ws + 165675008);   // 2 x 2,097,152
    int*   rowpB = (int*) (ws + 169869312);   // 2 x 262,400
    int*   cntB  = (int*) (ws + 170394112);   // 2 x 262,144
    float* dinvB = (float*)(ws + 170918400);  // 2 x 262,144
    float* xc   = (float*)(ws + 171442688);   // 1,048,576
    float* xc1  = (float*)(ws + 172491264);   // 524,288
    float* xc2  = (float*)(ws + 173015552);   // 131,072
    unsigned short* wt    = (unsigned short*)(ws + 173146624); // conv weights 786,432 B
    unsigned short* wtfc1 = (unsigned short*)(ws + 173933056); // 2 x 1,310,720 B
    unsigned short* wtfc2 = (unsigned short*)(ws + 176554496); // 2 x 524,288 B
    unsigned short* wtxt  = (unsigned short*)(ws + 177603072); // 524,288 B
    // total ws use: 178,127,360 B

    // CSR-build scratch aliases Ahb/Alb (dead until convs start)
    unsigned int* bbuf = (unsigned int*)Ahb;   // 512*3072*4 = 6,291,456 B
    int*          bcnt = (int*)Alb;            // 2048 B

    float* xpad = Y3;
    float* y1   = Y3;
    float* y2   = (float*)S2;
    unsigned short* Ph = (unsigned short*)(S2 + 0);
    unsigned short* Pl = (unsigned short*)(S2 + 655360);
    unsigned short* Fh = (unsigned short*)(S2 + 1310720);
    unsigned short* Fl = (unsigned short*)(S2 + 3407872);
    unsigned short* Th = (unsigned short*)(S2 + 5505024);
    unsigned short* Tl = (unsigned short*)(S2 + 7602176);
    float* pooled = (float*)(S2 + 9699328);

    const int E = N_EDGES;

    const int Ks[3]  = { FD, FD, FD * 2 };
    const int Ns[3]  = { FD, FD * 2, FD * 4 };
    const int Kps[3] = { 96, 96, 160 };
    const int Nps[3] = { 128, 256, 384 };
    const int Ss[3]  = { 80, 80, 160 };
    const int Ldc[3] = { 80, 160, 312 };
    const int wtoff[3] = { 0, 24576, 73728 };
    const int WT_BRANCH = 196608;

    // ---- batched weight prep (1 launch) ----
    PrepArgs pa;
    for (int br = 0; br < 2; ++br) {
        int base = 7 + br * 10;
        for (int c = 0; c < 3; ++c) {
            unsigned short* wh = wt + br * WT_BRANCH + wtoff[c];
            pa.d[br * 3 + c] = { (const float*)d_in[base + 2 * c], wh,
                                 wh + Nps[c] * Kps[c], Ks[c], Ns[c], Kps[c], Nps[c] };
        }
        pa.d[6 + br] = { (const float*)d_in[base + 6], wtfc1 + br * 655360,
                         wtfc1 + br * 655360 + 327680, FD * 4, 1024, 320, 1024 };
        pa.d[8 + br] = { (const float*)d_in[base + 8], wtfc2 + br * 262144,
                         wtfc2 + br * 262144 + 131072, 1024, 64, 1024, 128 };
    }
    pa.d[10] = { xt_w, wtxt, wtxt + 131072, 1000, 128, 1024, 128 };
    prep_all<<<dim3(256, 11), 256, 0, stream>>>(pa);

    // ---- bucketed CSR build, both branches ----
    const int* src1 = ei1, *dst1 = ei1 + E;
    const int* src2 = ei2, *dst2 = ei2 + E;
    hipMemsetAsync(bcnt, 0, 512 * sizeof(int), stream);
    bucket_scatter<<<2 * (E / EPB), 1024, 0, stream>>>(src1, dst1, src2, dst2, bcnt, bbuf, E);
    bucket_count<<<512, 256, 0, stream>>>(bcnt, bbuf, cntB);
    make_dinv2<<<(2 * N_NODES + 255) / 256, 256, 0, stream>>>(cntB, dinvB);
    scan_rowptr<<<2, 1024, 0, stream>>>(cntB, rowpB);
    bucket_sort<<<512, 256, 0, stream>>>(bcnt, bbuf, rowpB, csrsB);

    // xc accumulated by split-K atomics -> zero it up front
    hipMemsetAsync(xc, 0, N_GRAPHS * 256 * sizeof(float), stream);

    for (int br = 0; br < 2; ++br) {
        const float* x = br == 0 ? x1 : x2;
        const int* rowp = rowpB + br * RPS;
        const int* csr  = csrsB + br * E;
        const float* dv = dinvB + br * N_NODES;
        int base = 7 + br * 10;
        const float* bias_c[3] = { (const float*)d_in[base + 1], (const float*)d_in[base + 3],
                                   (const float*)d_in[base + 5] };
        const float* bfc1b = (const float*)d_in[base + 7];
        const float* bfc2b = (const float*)d_in[base + 9];

        repack_pad<<<(N_NODES * 80 + 255) / 256, 256, 0, stream>>>(x, xpad, FD, 80);

        const float* cin[3]  = { xpad, y1, y2 };
        float*       cout[3] = { y1, y2, pooled };
        for (int c = 0; c < 3; ++c) {
            int Kp = Kps[c], Np = Nps[c], S = Ss[c];
            int total = N_NODES * (Kp >> 3);
            gather8<<<(total + 255) / 256, 256, 0, stream>>>(
                cin[c], rowp, csr, dv, Ahb, Alb, S, Kp);
            if (c == 2) {
                hipMemsetAsync(pooled, 0, N_GRAPHS * 320 * sizeof(float), stream);
                gemm_mfma<<<dim3(Np / 128, 512), 256, 0, stream>>>(
                    Ahb, Alb, wt + br * WT_BRANCH + wtoff[c],
                    wt + br * WT_BRANCH + wtoff[c] + Np * Kp, bias_c[c],
                    pooled, nullptr, nullptr, Ns[c], Kp, 320, 1, 0, 2);
            } else {
                gemm_mfma<<<dim3(Np / 128, 512), 256, 0, stream>>>(
                    Ahb, Alb, wt + br * WT_BRANCH + wtoff[c],
                    wt + br * WT_BRANCH + wtoff[c] + Np * Kp, bias_c[c],
                    cout[c], nullptr, nullptr, Ns[c], Kp, Ldc[c], 1, 1, 0);
            }
        }

        // ---- branch MLP ----
        split_pad<<<(N_GRAPHS * 320 + 255) / 256, 256, 0, stream>>>(pooled, Ph, Pl, N_GRAPHS, 320, 320);
        gemm_mfma<<<dim3(8, 8), 256, 0, stream>>>(
            Ph, Pl, wtfc1 + br * 655360, wtfc1 + br * 655360 + 327680, bfc1b,
            nullptr, Fh, Fl, 1024, 320, 1024, 1, 1, 1);
        gemm_mfma_sk<<<dim3(1, 8, 8), 256, 0, stream>>>(
            Fh, Fl, wtfc2 + br * 262144, wtfc2 + br * 262144 + 131072, bfc2b,
            xc + br * 64, 1024, 256, 128);
    }

    // xt
    split_pad<<<(1024 * 1024 + 255) / 256, 256, 0, stream>>>(target, Th, Tl, 1024, 1000, 1024);
    gemm_mfma_sk<<<dim3(2, 8, 8), 256, 0, stream>>>(
        Th, Tl, wtxt, wtxt + 131072, xt_b,
        xc + 128, 1024, 256, 128);

    // head
    fc_launch(xc,  fc1_w, fc1_b, xc1, N_GRAPHS, 128, 256, 256, 128, 1, stream);
    fc_launch(xc1, fc2_w, fc2_b, xc2, N_GRAPHS, 32, 128, 128, 32, 1, stream);
    fc_launch(xc2, out_w, out_b, (float*)d_out, N_GRAPHS, 1, 32, 32, 1, 0, stream);
}

// Round 12
// 519.161 us; speedup vs baseline: 1.9416x; 1.1287x over previous
//
#include <hip/hip_runtime.h>
#include <hip/hip_bf16.h>
#include <math.h>

#define N_NODES 65536
#define N_EDGES 524288
#define N_GRAPHS 1024
#define NPG 64
#define FD 78
#define RPS 65600   // row_ptr stride (ints) per branch
#define BCAP 3072   // per-bucket edge capacity (mean 2048, >20 sigma)
#define EPB 4096    // edges per scatter block

typedef __attribute__((ext_vector_type(8))) short bf16x8;
typedef __attribute__((ext_vector_type(4))) float f32x4;

__device__ __forceinline__ unsigned short f2bf(float v) {
    unsigned int u = __float_as_uint(v);
    unsigned int r = (u + 0x7FFFu + ((u >> 16) & 1u)) >> 16;
    return (unsigned short)r;
}
__device__ __forceinline__ float bf2f(unsigned short h) {
    return __uint_as_float(((unsigned int)h) << 16);
}

// ---------------- split-bf16 MFMA GEMM, reg-prefetch pipelined, branch-merged ----------------
// A holds BOTH branches' rows contiguously; branch b = blockIdx.y >> brshift selects W/bias.
// omode 0: f32 to Cf; omode 1: hi/lo bf16 to Ch/Cl; omode 2: fused 64-row max-pool.
__global__ __launch_bounds__(256, 3) void gemm_mfma(
    const unsigned short* __restrict__ Ah, const unsigned short* __restrict__ Al,
    const unsigned short* __restrict__ Wh0, const unsigned short* __restrict__ Wl0,
    const unsigned short* __restrict__ Wh1, const unsigned short* __restrict__ Wl1,
    const float* __restrict__ bias0, const float* __restrict__ bias1,
    float* __restrict__ Cf, unsigned short* __restrict__ Ch, unsigned short* __restrict__ Cl,
    int N, int Kp, int ldc, int relu, int zpad, int omode, int brshift)
{
    __shared__ __align__(16) unsigned short sAh[128][40];
    __shared__ __align__(16) unsigned short sAl[128][40];
    __shared__ __align__(16) unsigned short sBh[128][40];
    __shared__ __align__(16) unsigned short sBl[128][40];

    int tid = threadIdx.x;
    int bm = blockIdx.y << 7;
    int bn = blockIdx.x << 7;
    int b = blockIdx.y >> brshift;
    const unsigned short* Wh = b ? Wh1 : Wh0;
    const unsigned short* Wl = b ? Wl1 : Wl0;
    const float* bias = b ? bias1 : bias0;

    int lane = tid & 63;
    int wid = tid >> 6;
    int wr = wid >> 1, wc = wid & 1;
    int cr = lane & 15;
    int kg = lane >> 4;

    int r0 = tid >> 2;
    int sg = (tid & 3) * 8;
    const unsigned short* pAh = Ah + (size_t)(bm + r0) * Kp + sg;
    const unsigned short* pAl = Al + (size_t)(bm + r0) * Kp + sg;
    const unsigned short* pBh = Wh + (size_t)(bn + r0) * Kp + sg;
    const unsigned short* pBl = Wl + (size_t)(bn + r0) * Kp + sg;
    size_t rstep = (size_t)64 * Kp;

    uint4 vAh0, vAh1, vAl0, vAl1, vBh0, vBh1, vBl0, vBl1;
    auto LOADT = [&](int k0) {
        vAh0 = *(const uint4*)(pAh + k0);
        vAh1 = *(const uint4*)(pAh + k0 + rstep);
        vAl0 = *(const uint4*)(pAl + k0);
        vAl1 = *(const uint4*)(pAl + k0 + rstep);
        vBh0 = *(const uint4*)(pBh + k0);
        vBh1 = *(const uint4*)(pBh + k0 + rstep);
        vBl0 = *(const uint4*)(pBl + k0);
        vBl1 = *(const uint4*)(pBl + k0 + rstep);
    };
    auto WRITET = [&]() {
        *(uint4*)&sAh[r0][sg] = vAh0;
        *(uint4*)&sAh[r0 + 64][sg] = vAh1;
        *(uint4*)&sAl[r0][sg] = vAl0;
        *(uint4*)&sAl[r0 + 64][sg] = vAl1;
        *(uint4*)&sBh[r0][sg] = vBh0;
        *(uint4*)&sBh[r0 + 64][sg] = vBh1;
        *(uint4*)&sBl[r0][sg] = vBl0;
        *(uint4*)&sBl[r0 + 64][sg] = vBl1;
    };

    f32x4 acc[4][4] = {};

    LOADT(0);
    WRITET();
    __syncthreads();

    for (int k0 = 0; k0 < Kp; k0 += 32) {
        int more = (k0 + 32) < Kp;
        if (more) LOADT(k0 + 32);

        bf16x8 bH[4], bL[4];
        #pragma unroll
        for (int nf = 0; nf < 4; ++nf) {
            bH[nf] = *(const bf16x8*)&sBh[wc * 64 + nf * 16 + cr][kg * 8];
            bL[nf] = *(const bf16x8*)&sBl[wc * 64 + nf * 16 + cr][kg * 8];
        }
        #pragma unroll
        for (int mf = 0; mf < 4; ++mf) {
            bf16x8 aH = *(const bf16x8*)&sAh[wr * 64 + mf * 16 + cr][kg * 8];
            bf16x8 aL = *(const bf16x8*)&sAl[wr * 64 + mf * 16 + cr][kg * 8];
            #pragma unroll
            for (int nf = 0; nf < 4; ++nf) {
                acc[mf][nf] = __builtin_amdgcn_mfma_f32_16x16x32_bf16(aH, bH[nf], acc[mf][nf], 0, 0, 0);
                acc[mf][nf] = __builtin_amdgcn_mfma_f32_16x16x32_bf16(aH, bL[nf], acc[mf][nf], 0, 0, 0);
                acc[mf][nf] = __builtin_amdgcn_mfma_f32_16x16x32_bf16(aL, bH[nf], acc[mf][nf], 0, 0, 0);
            }
        }
        __syncthreads();
        if (more) {
            WRITET();
            __syncthreads();
        }
    }

    if (omode == 2) {
        // fused graph max-pool: wave tile = 64 rows = one graph; g spans both branches
        int g = (blockIdx.y << 1) + wr;
        #pragma unroll
        for (int nf = 0; nf < 4; ++nf) {
            int col = bn + wc * 64 + nf * 16 + cr;
            if (col < N) {
                float m = -INFINITY;
                #pragma unroll
                for (int mf = 0; mf < 4; ++mf) {
                    f32x4 v = acc[mf][nf];
                    #pragma unroll
                    for (int j = 0; j < 4; ++j) m = fmaxf(m, v[j]);
                }
                m = fmaxf(m + bias[col], 0.f);
                m = fmaxf(m, __shfl_xor(m, 16, 64));
                m = fmaxf(m, __shfl_xor(m, 32, 64));
                if (kg == 0)
                    atomicMax((unsigned int*)&Cf[(size_t)g * ldc + col], __float_as_uint(m));
            }
        }
        return;
    }

    #pragma unroll
    for (int mf = 0; mf < 4; ++mf) {
        int rowbase = bm + wr * 64 + mf * 16 + kg * 4;
        #pragma unroll
        for (int nf = 0; nf < 4; ++nf) {
            int col = bn + wc * 64 + nf * 16 + cr;
            if (col >= ldc) continue;
            int live = col < N;
            if (!live && !zpad) continue;
            float bv = live ? bias[col] : 0.f;
            f32x4 v = acc[mf][nf];
            #pragma unroll
            for (int j = 0; j < 4; ++j) {
                size_t idx = (size_t)(rowbase + j) * ldc + col;
                float o = v[j] + bv;
                if (relu) o = fmaxf(o, 0.f);
                if (!live) o = 0.f;
                if (omode == 0) {
                    Cf[idx] = o;
                } else {
                    unsigned short h = f2bf(o);
                    Ch[idx] = h;
                    Cl[idx] = f2bf(o - bf2f(h));
                }
            }
        }
    }
}

// ---------------- split-K MFMA GEMM for skinny FCs (branch-merged) ----------------
// branch b = blockIdx.y >> brshift; row_local = row - b*1024; output col += b*colstep.
__global__ __launch_bounds__(256) void gemm_mfma_sk(
    const unsigned short* __restrict__ Ah, const unsigned short* __restrict__ Al,
    const unsigned short* __restrict__ Wh0, const unsigned short* __restrict__ Wl0,
    const unsigned short* __restrict__ Wh1, const unsigned short* __restrict__ Wl1,
    const float* __restrict__ bias0, const float* __restrict__ bias1,
    float* __restrict__ C, int Kp, int ldc, int kchunk, int brshift, int colstep)
{
    __shared__ __align__(16) unsigned short sAh[128][40];
    __shared__ __align__(16) unsigned short sAl[128][40];
    __shared__ __align__(16) unsigned short sBh[64][40];
    __shared__ __align__(16) unsigned short sBl[64][40];

    int tid = threadIdx.x;
    int bm = blockIdx.y << 7;
    int bn = blockIdx.x << 6;
    int b = blockIdx.y >> brshift;
    const unsigned short* Wh = b ? Wh1 : Wh0;
    const unsigned short* Wl = b ? Wl1 : Wl0;
    const float* bias = b ? bias1 : bias0;
    int rowoff = bm - (b << 10);
    int kbase = blockIdx.z * kchunk;
    int lane = tid & 63;
    int wid = tid >> 6;
    int wr = wid >> 1, wc = wid & 1;
    int cr = lane & 15;
    int kg = lane >> 4;

    f32x4 acc[4][2] = {};

    for (int k0 = kbase; k0 < kbase + kchunk; k0 += 32) {
        #pragma unroll
        for (int s = tid; s < 512; s += 256) {
            int r = s >> 2, seg = s & 3;
            *(uint4*)&sAh[r][seg * 8] =
                *(const uint4*)(Ah + (size_t)(bm + r) * Kp + k0 + seg * 8);
        }
        #pragma unroll
        for (int s = tid; s < 512; s += 256) {
            int r = s >> 2, seg = s & 3;
            *(uint4*)&sAl[r][seg * 8] =
                *(const uint4*)(Al + (size_t)(bm + r) * Kp + k0 + seg * 8);
        }
        {
            int r = tid >> 2, seg = tid & 3;
            *(uint4*)&sBh[r][seg * 8] =
                *(const uint4*)(Wh + (size_t)(bn + r) * Kp + k0 + seg * 8);
            *(uint4*)&sBl[r][seg * 8] =
                *(const uint4*)(Wl + (size_t)(bn + r) * Kp + k0 + seg * 8);
        }
        __syncthreads();

        bf16x8 bH[2], bL[2];
        #pragma unroll
        for (int nf = 0; nf < 2; ++nf) {
            bH[nf] = *(const bf16x8*)&sBh[wc * 32 + nf * 16 + cr][kg * 8];
            bL[nf] = *(const bf16x8*)&sBl[wc * 32 + nf * 16 + cr][kg * 8];
        }
        #pragma unroll
        for (int mf = 0; mf < 4; ++mf) {
            bf16x8 aH = *(const bf16x8*)&sAh[wr * 64 + mf * 16 + cr][kg * 8];
            bf16x8 aL = *(const bf16x8*)&sAl[wr * 64 + mf * 16 + cr][kg * 8];
            #pragma unroll
            for (int nf = 0; nf < 2; ++nf) {
                acc[mf][nf] = __builtin_amdgcn_mfma_f32_16x16x32_bf16(aH, bH[nf], acc[mf][nf], 0, 0, 0);
                acc[mf][nf] = __builtin_amdgcn_mfma_f32_16x16x32_bf16(aH, bL[nf], acc[mf][nf], 0, 0, 0);
                acc[mf][nf] = __builtin_amdgcn_mfma_f32_16x16x32_bf16(aL, bH[nf], acc[mf][nf], 0, 0, 0);
            }
        }
        __syncthreads();
    }

    int z0 = blockIdx.z == 0;
    #pragma unroll
    for (int mf = 0; mf < 4; ++mf) {
        int rowbase = rowoff + wr * 64 + mf * 16 + kg * 4;
        #pragma unroll
        for (int nf = 0; nf < 2; ++nf) {
            int cl = bn + wc * 32 + nf * 16 + cr;
            float bv = z0 ? bias[cl] : 0.f;
            int col = b * colstep + cl;
            f32x4 v = acc[mf][nf];
            #pragma unroll
            for (int j = 0; j < 4; ++j)
                atomicAdd(&C[(size_t)(rowbase + j) * ldc + col], v[j] + bv);
        }
    }
}

// ---------------- batched weight prep ----------------
struct PrepDesc { const float* W; unsigned short* Wh; unsigned short* Wl; int K, N, Kp, Np; };
struct PrepArgs { PrepDesc d[11]; };

__global__ void prep_all(PrepArgs pa) {
    PrepDesc de = pa.d[blockIdx.y];
    int tot = de.Np * de.Kp;
    for (int t = blockIdx.x * blockDim.x + threadIdx.x; t < tot; t += gridDim.x * blockDim.x) {
        int n = t / de.Kp, k = t - n * de.Kp;
        float v = (n < de.N && k < de.K) ? de.W[(size_t)k * de.N + n] : 0.f;
        unsigned short h = f2bf(v);
        de.Wh[t] = h;
        de.Wl[t] = f2bf(v - bf2f(h));
    }
}

// ---------------- f32 [M,F] -> hi/lo split, zero-padded to Kp ----------------
__global__ void split_pad(const float* __restrict__ x, unsigned short* __restrict__ Xh,
                          unsigned short* __restrict__ Xl, int M, int F, int Kp) {
    int t = blockIdx.x * blockDim.x + threadIdx.x;
    if (t >= M * Kp) return;
    int i = t / Kp, c = t - i * Kp;
    float v = (c < F) ? x[(size_t)i * F + c] : 0.f;
    unsigned short h = f2bf(v);
    Xh[t] = h;
    Xl[t] = f2bf(v - bf2f(h));
}

// ---------------- small-M FC (head only) ----------------
__global__ __launch_bounds__(256) void fc_row(
    const float* __restrict__ A, const float* __restrict__ B,
    const float* __restrict__ bias, float* __restrict__ C,
    int M, int N, int K, int lda, int ldc, int relu)
{
    int nchunks = (N + 63) >> 6;
    int bid = blockIdx.x;
    int nc = bid % nchunks;
    int m = ((bid / nchunks) << 2) + (threadIdx.x >> 6);
    int lane = threadIdx.x & 63;
    if (m >= M) return;
    int n = (nc << 6) + lane;
    int nclamp = n < N ? n : N - 1;
    const float* __restrict__ a = A + (size_t)m * lda;
    const float* __restrict__ bp = B + nclamp;
    float acc = 0.f;
    int kk = 0;
    #pragma unroll 4
    for (; kk + 4 <= K; kk += 4) {
        float a0 = a[kk + 0], a1 = a[kk + 1], a2 = a[kk + 2], a3 = a[kk + 3];
        float b0 = bp[(size_t)(kk + 0) * N];
        float b1 = bp[(size_t)(kk + 1) * N];
        float b2 = bp[(size_t)(kk + 2) * N];
        float b3 = bp[(size_t)(kk + 3) * N];
        acc = fmaf(a0, b0, acc);
        acc = fmaf(a1, b1, acc);
        acc = fmaf(a2, b2, acc);
        acc = fmaf(a3, b3, acc);
    }
    for (; kk < K; ++kk)
        acc = fmaf(a[kk], bp[(size_t)kk * N], acc);
    if (n < N) {
        float v = acc + bias[n];
        if (relu) v = fmaxf(v, 0.f);
        C[(size_t)m * ldc + n] = v;
    }
}

// ---------------- bucketed CSR build (two-level scatter) ----------------
__global__ __launch_bounds__(1024) void bucket_scatter(
    const int* __restrict__ s1, const int* __restrict__ d1,
    const int* __restrict__ s2, const int* __restrict__ d2,
    int* __restrict__ bcnt, unsigned int* __restrict__ bbuf, int E)
{
    __shared__ int lhist[256];
    __shared__ int lbase[256];
    int nblk = E / EPB;
    int b = blockIdx.x >= nblk;
    int blk = blockIdx.x - b * nblk;
    const int* sp = b ? s2 : s1;
    const int* dp = b ? d2 : d1;
    int e0 = blk * EPB;
    if (threadIdx.x < 256) lhist[threadIdx.x] = 0;
    __syncthreads();

    unsigned int pack[EPB / 1024];
    int bkt[EPB / 1024], rank[EPB / 1024];
    #pragma unroll
    for (int i = 0; i < EPB / 1024; ++i) {
        int e = e0 + threadIdx.x + i * 1024;
        int s = sp[e], d = dp[e];
        bkt[i] = d >> 8;
        pack[i] = ((unsigned int)s << 8) | (unsigned int)(d & 255);
        rank[i] = atomicAdd(&lhist[bkt[i]], 1);
    }
    __syncthreads();
    if (threadIdx.x < 256) {
        int c = lhist[threadIdx.x];
        lbase[threadIdx.x] = c ? atomicAdd(&bcnt[(b << 8) | threadIdx.x], c) : 0;
    }
    __syncthreads();
    #pragma unroll
    for (int i = 0; i < EPB / 1024; ++i) {
        int pos = lbase[bkt[i]] + rank[i];
        if (pos < BCAP)
            bbuf[(size_t)((b << 8) | bkt[i]) * BCAP + pos] = pack[i];
    }
}

__global__ __launch_bounds__(256) void bucket_count(const int* __restrict__ bcnt,
                                                    const unsigned int* __restrict__ bbuf,
                                                    int* __restrict__ cntB) {
    __shared__ int lc[256];
    int bk = blockIdx.x;
    lc[threadIdx.x] = 0;
    __syncthreads();
    int n = bcnt[bk]; if (n > BCAP) n = BCAP;
    const unsigned int* p = bbuf + (size_t)bk * BCAP;
    for (int i = threadIdx.x; i < n; i += 256)
        atomicAdd(&lc[p[i] & 255u], 1);
    __syncthreads();
    int br = bk >> 8, nb = (bk & 255) << 8;
    cntB[br * N_NODES + nb + threadIdx.x] = lc[threadIdx.x];
}

__global__ __launch_bounds__(256) void bucket_sort(const int* __restrict__ bcnt,
                                                   const unsigned int* __restrict__ bbuf,
                                                   const int* __restrict__ rowpB,
                                                   int* __restrict__ csrsB) {
    __shared__ int lrow[256];
    __shared__ int lcur[256];
    int bk = blockIdx.x;
    int br = bk >> 8, nb = (bk & 255) << 8;
    lrow[threadIdx.x] = rowpB[br * RPS + nb + threadIdx.x];
    lcur[threadIdx.x] = 0;
    __syncthreads();
    int n = bcnt[bk]; if (n > BCAP) n = BCAP;
    const unsigned int* p = bbuf + (size_t)bk * BCAP;
    int* outp = csrsB + (size_t)br * N_EDGES;
    for (int i = threadIdx.x; i < n; i += 256) {
        unsigned int e = p[i];
        int dl = e & 255u;
        int pos = lrow[dl] + atomicAdd(&lcur[dl], 1);
        outp[pos] = (int)(e >> 8);
    }
}

__global__ void make_dinv2(const int* __restrict__ cnt, float* __restrict__ dinv) {
    int t = blockIdx.x * blockDim.x + threadIdx.x;
    if (t < 2 * N_NODES) dinv[t] = rsqrtf((float)cnt[t] + 1.0f);
}

__global__ __launch_bounds__(1024) void scan_rowptr(const int* __restrict__ cntB,
                                                    int* __restrict__ rowpB) {
    __shared__ int sums[1024];
    const int* cnt = cntB + blockIdx.x * N_NODES;
    int* row_ptr = rowpB + blockIdx.x * RPS;
    int t = threadIdx.x;
    int base = t * 64;
    int s = 0;
    #pragma unroll 4
    for (int i = 0; i < 64; ++i) s += cnt[base + i];
    sums[t] = s;
    __syncthreads();
    for (int off = 1; off < 1024; off <<= 1) {
        int v = sums[t];
        int add = (t >= off) ? sums[t - off] : 0;
        __syncthreads();
        sums[t] = v + add;
        __syncthreads();
    }
    int run = (t == 0) ? 0 : sums[t - 1];
    for (int i = 0; i < 64; ++i) {
        row_ptr[base + i] = run;
        run += cnt[base + i];
    }
    if (t == 1023) row_ptr[N_NODES] = run;
}

// pad-repack both branches: x1/x2 [65536,78] -> xp [131072,80]
__global__ void repack_pad2(const float* __restrict__ x1, const float* __restrict__ x2,
                            float* __restrict__ xp) {
    int t = blockIdx.x * blockDim.x + threadIdx.x;
    int total = 2 * N_NODES * 80;
    if (t >= total) return;
    int i = t / 80, c = t - i * 80;
    int b = i >> 16, il = i & 65535;
    const float* x = b ? x2 : x1;
    xp[t] = (c < FD) ? x[(size_t)il * FD + c] : 0.f;
}

// gather + normalize + split, both branches; 8 features/thread, edge loop x4
__global__ __launch_bounds__(256) void gather8(
    const float* __restrict__ x, const int* __restrict__ rowpB,
    const int* __restrict__ csrsB, const float* __restrict__ dinvB,
    unsigned short* __restrict__ Ah, unsigned short* __restrict__ Al,
    int S, int Kp)
{
    int Kp8 = Kp >> 3;
    int t = blockIdx.x * blockDim.x + threadIdx.x;
    int total = 2 * N_NODES * Kp8;
    if (t >= total) return;
    int i = t / Kp8;                 // global row 0..131071
    int g = t - i * Kp8;
    int f = g << 3;
    size_t ob = (size_t)i * Kp + f;
    if (f >= S) {
        bf16x8 z = {};
        *(bf16x8*)&Ah[ob] = z;
        *(bf16x8*)&Al[ob] = z;
        return;
    }
    int b = i >> 16, il = i & 65535;
    const int* rowp = rowpB + b * RPS;
    const int* csrs = csrsB + (size_t)b * N_EDGES;
    const float* dinv = dinvB + ((size_t)b << 16);
    const float* xb = x + (((size_t)b << 16) * S);
    float di = dinv[il];
    const float* xr = x + (size_t)i * S + f;
    f32x4 s0 = *(const f32x4*)xr;
    f32x4 s1 = *(const f32x4*)(xr + 4);
    float w = di * di;
    s0 *= w;
    s1 *= w;
    int p0 = rowp[il], p1 = rowp[il + 1];
    int p = p0;
    for (; p + 4 <= p1; p += 4) {
        int sa = csrs[p], sb = csrs[p + 1], sc = csrs[p + 2], sd = csrs[p + 3];
        float ca = dinv[sa] * di, cb = dinv[sb] * di;
        float cc = dinv[sc] * di, cd = dinv[sd] * di;
        const float* ra = xb + (size_t)sa * S + f;
        const float* rb = xb + (size_t)sb * S + f;
        const float* rc = xb + (size_t)sc * S + f;
        const float* rd = xb + (size_t)sd * S + f;
        f32x4 a0 = *(const f32x4*)ra, a1 = *(const f32x4*)(ra + 4);
        f32x4 b0 = *(const f32x4*)rb, b1 = *(const f32x4*)(rb + 4);
        f32x4 c0 = *(const f32x4*)rc, c1 = *(const f32x4*)(rc + 4);
        f32x4 d0 = *(const f32x4*)rd, d1 = *(const f32x4*)(rd + 4);
        s0 += ca * a0 + cb * b0 + cc * c0 + cd * d0;
        s1 += ca * a1 + cb * b1 + cc * c1 + cd * d1;
    }
    for (; p < p1; ++p) {
        int sa = csrs[p];
        float ca = dinv[sa] * di;
        const float* ra = xb + (size_t)sa * S + f;
        s0 += ca * *(const f32x4*)ra;
        s1 += ca * *(const f32x4*)(ra + 4);
    }
    bf16x8 hh, ll;
    #pragma unroll
    for (int j = 0; j < 4; ++j) {
        unsigned short h0 = f2bf(s0[j]);
        hh[j] = (short)h0;
        ll[j] = (short)f2bf(s0[j] - bf2f(h0));
        unsigned short h1 = f2bf(s1[j]);
        hh[4 + j] = (short)h1;
        ll[4 + j] = (short)f2bf(s1[j] - bf2f(h1));
    }
    *(bf16x8*)&Ah[ob] = hh;
    *(bf16x8*)&Al[ob] = ll;
}

// ---------------- host side ----------------
static inline void fc_launch(const float* A, const float* B, const float* bias, float* C,
                             int M, int N, int K, int lda, int ldc, int relu, hipStream_t s) {
    int nchunks = (N + 63) / 64;
    int mblocks = (M + 3) / 4;
    fc_row<<<nchunks * mblocks, 256, 0, s>>>(A, B, bias, C, M, N, K, lda, ldc, relu);
}

extern "C" void kernel_launch(void* const* d_in, const int* in_sizes, int n_in,
                              void* d_out, int out_size, void* d_ws, size_t ws_size,
                              hipStream_t stream) {
    (void)in_sizes; (void)n_in; (void)out_size; (void)ws_size;

    const float* x1     = (const float*)d_in[0];
    const int*   ei1    = (const int*)d_in[1];
    const float* x2     = (const float*)d_in[3];
    const int*   ei2    = (const int*)d_in[4];
    const float* target = (const float*)d_in[6];

    const float* xt_w  = (const float*)d_in[27];
    const float* xt_b  = (const float*)d_in[28];
    const float* fc1_w = (const float*)d_in[29];
    const float* fc1_b = (const float*)d_in[30];
    const float* fc2_w = (const float*)d_in[31];
    const float* fc2_b = (const float*)d_in[32];
    const float* out_w = (const float*)d_in[33];
    const float* out_b = (const float*)d_in[34];

    char* ws = (char*)d_ws;
    // merged-branch layout (total 180,224,512 B)
    unsigned short* AhB = (unsigned short*)(ws + 0);           // 41,943,040 (131072 x 160 max)
    unsigned short* AlB = (unsigned short*)(ws + 41943040);    // 41,943,040
    float* R1   = (float*)(ws + 83886080);     // 41,943,040: xpad/y1 [131072][80]
    float* Y2   = (float*)(ws + 83886080);     // 83,886,080: y2 [131072][160] (overlays R1 after y1 dead)
    char*  FCS  = ws + 83886080;               // fc scratch (after y2 dead)
    int*   csrsB = (int*) (ws + 167772160);    // 4,194,304
    int*   rowpB = (int*) (ws + 171966464);    // 524,800
    int*   cntB  = (int*) (ws + 172491264);    // 524,288
    float* dinvB = (float*)(ws + 173015552);   // 524,288
    float* xc   = (float*)(ws + 173539840);    // 1,048,576
    float* xc1  = (float*)(ws + 174588416);    // 524,288
    float* xc2  = (float*)(ws + 175112704);    // 131,072
    unsigned short* wt    = (unsigned short*)(ws + 175243776); // 786,432
    unsigned short* wtfc1 = (unsigned short*)(ws + 176030208); // 2,621,440
    unsigned short* wtfc2 = (unsigned short*)(ws + 178651648); // 1,048,576
    unsigned short* wtxt  = (unsigned short*)(ws + 179700224); // 524,288

    // CSR-build scratch aliases AhB/AlB (dead until convs)
    unsigned int* bbuf = (unsigned int*)AhB;   // 6,291,456
    int*          bcnt = (int*)AlB;            // 2,048

    float* xpad = R1;
    float* y1   = R1;
    float* y2   = Y2;
    // fc scratch (alias y2 region; only used after gather3 consumed y2)
    float*          pooled = (float*)(FCS + 0);          // 2048x320 f32 = 2,621,440
    unsigned short* Ph = (unsigned short*)(FCS + 2621440);   // 1,310,720
    unsigned short* Pl = (unsigned short*)(FCS + 3932160);   // 1,310,720
    unsigned short* Fh = (unsigned short*)(FCS + 5242880);   // 4,194,304
    unsigned short* Fl = (unsigned short*)(FCS + 9437184);   // 4,194,304
    unsigned short* Th = (unsigned short*)(FCS + 13631488);  // 2,097,152
    unsigned short* Tl = (unsigned short*)(FCS + 15728640);  // 2,097,152

    const int E = N_EDGES;

    const int Ks[3]  = { FD, FD, FD * 2 };
    const int Ns[3]  = { FD, FD * 2, FD * 4 };
    const int Kps[3] = { 96, 96, 160 };
    const int Nps[3] = { 128, 256, 384 };
    const int Ss[3]  = { 80, 80, 160 };
    const int Ldc[3] = { 80, 160, 320 };      // conv3 ldc = pooled stride 320
    const int wtoff[3] = { 0, 24576, 73728 };
    const int WT_BRANCH = 196608;

    // ---- batched weight prep (1 launch) ----
    PrepArgs pa;
    for (int br = 0; br < 2; ++br) {
        int base = 7 + br * 10;
        for (int c = 0; c < 3; ++c) {
            unsigned short* wh = wt + br * WT_BRANCH + wtoff[c];
            pa.d[br * 3 + c] = { (const float*)d_in[base + 2 * c], wh,
                                 wh + Nps[c] * Kps[c], Ks[c], Ns[c], Kps[c], Nps[c] };
        }
        pa.d[6 + br] = { (const float*)d_in[base + 6], wtfc1 + br * 655360,
                         wtfc1 + br * 655360 + 327680, FD * 4, 1024, 320, 1024 };
        pa.d[8 + br] = { (const float*)d_in[base + 8], wtfc2 + br * 262144,
                         wtfc2 + br * 262144 + 131072, 1024, 64, 1024, 128 };
    }
    pa.d[10] = { xt_w, wtxt, wtxt + 131072, 1000, 128, 1024, 128 };
    prep_all<<<dim3(256, 11), 256, 0, stream>>>(pa);

    // ---- bucketed CSR build, both branches ----
    const int* src1 = ei1, *dst1 = ei1 + E;
    const int* src2 = ei2, *dst2 = ei2 + E;
    hipMemsetAsync(bcnt, 0, 512 * sizeof(int), stream);
    bucket_scatter<<<2 * (E / EPB), 1024, 0, stream>>>(src1, dst1, src2, dst2, bcnt, bbuf, E);
    bucket_count<<<512, 256, 0, stream>>>(bcnt, bbuf, cntB);
    make_dinv2<<<(2 * N_NODES + 255) / 256, 256, 0, stream>>>(cntB, dinvB);
    scan_rowptr<<<2, 1024, 0, stream>>>(cntB, rowpB);
    bucket_sort<<<512, 256, 0, stream>>>(bcnt, bbuf, rowpB, csrsB);

    hipMemsetAsync(xc, 0, N_GRAPHS * 256 * sizeof(float), stream);

    // ---- merged conv chain (both branches per dispatch) ----
    repack_pad2<<<(2 * N_NODES * 80 + 255) / 256, 256, 0, stream>>>(x1, x2, xpad);

    const float* cin[3]  = { xpad, y1, y2 };
    float*       cout[3] = { y1, y2, pooled };
    const float* biasc[2][3];
    for (int br = 0; br < 2; ++br) {
        int base = 7 + br * 10;
        biasc[br][0] = (const float*)d_in[base + 1];
        biasc[br][1] = (const float*)d_in[base + 3];
        biasc[br][2] = (const float*)d_in[base + 5];
    }

    for (int c = 0; c < 3; ++c) {
        int Kp = Kps[c], Np = Nps[c], S = Ss[c];
        int total = 2 * N_NODES * (Kp >> 3);
        gather8<<<(total + 255) / 256, 256, 0, stream>>>(
            cin[c], rowpB, csrsB, dinvB, AhB, AlB, S, Kp);
        unsigned short* wh0 = wt + wtoff[c];
        unsigned short* wh1 = wt + WT_BRANCH + wtoff[c];
        if (c == 2) {
            hipMemsetAsync(pooled, 0, 2048 * 320 * sizeof(float), stream);
            gemm_mfma<<<dim3(Np / 128, 1024), 256, 0, stream>>>(
                AhB, AlB, wh0, wh0 + Np * Kp, wh1, wh1 + Np * Kp,
                biasc[0][2], biasc[1][2],
                pooled, nullptr, nullptr, Ns[c], Kp, 320, 1, 0, 2, 9);
        } else {
            gemm_mfma<<<dim3(Np / 128, 1024), 256, 0, stream>>>(
                AhB, AlB, wh0, wh0 + Np * Kp, wh1, wh1 + Np * Kp,
                biasc[0][c], biasc[1][c],
                cout[c], nullptr, nullptr, Ns[c], Kp, Ldc[c], 1, 1, 0, 9);
        }
    }

    // ---- merged branch MLP ----
    split_pad<<<(2048 * 320 + 255) / 256, 256, 0, stream>>>(pooled, Ph, Pl, 2048, 320, 320);
    // fc1 both branches: [2048,320] @ per-branch [1024,320]^T -> split [2048][1024], relu
    gemm_mfma<<<dim3(8, 16), 256, 0, stream>>>(
        Ph, Pl, wtfc1, wtfc1 + 327680, wtfc1 + 655360, wtfc1 + 655360 + 327680,
        (const float*)d_in[7 + 7], (const float*)d_in[17 + 7],
        nullptr, Fh, Fl, 1024, 320, 1024, 1, 1, 1, 3);
    // fc2 both branches: split-K -> xc cols [b*64, b*64+64)
    gemm_mfma_sk<<<dim3(1, 16, 8), 256, 0, stream>>>(
        Fh, Fl, wtfc2, wtfc2 + 131072, wtfc2 + 262144, wtfc2 + 262144 + 131072,
        (const float*)d_in[7 + 9], (const float*)d_in[17 + 9],
        xc, 1024, 256, 128, 3, 64);

    // xt: split target, split-K -> xc cols [128,256)
    split_pad<<<(1024 * 1024 + 255) / 256, 256, 0, stream>>>(target, Th, Tl, 1024, 1000, 1024);
    gemm_mfma_sk<<<dim3(2, 8, 8), 256, 0, stream>>>(
        Th, Tl, wtxt, wtxt + 131072, wtxt, wtxt + 131072, xt_b, xt_b,
        xc + 128, 1024, 256, 128, 30, 0);

    // head
    fc_launch(xc,  fc1_w, fc1_b, xc1, N_GRAPHS, 128, 256, 256, 128, 1, stream);
    fc_launch(xc1, fc2_w, fc2_b, xc2, N_GRAPHS, 32, 128, 128, 32, 1, stream);
    fc_launch(xc2, out_w, out_b, (float*)d_out, N_GRAPHS, 1, 32, 32, 1, 0, stream);
}

// Round 13
// 505.291 us; speedup vs baseline: 1.9949x; 1.0274x over previous
//
#include <hip/hip_runtime.h>
#include <hip/hip_bf16.h>
#include <math.h>

#define N_NODES 65536
#define N_EDGES 524288
#define N_GRAPHS 1024
#define NPG 64
#define FD 78
#define RPS 65600   // row_ptr stride (ints) per branch
#define BCAP 3072   // per-bucket edge capacity (mean 2048, >20 sigma)
#define EPB 4096    // edges per scatter block

typedef __attribute__((ext_vector_type(8))) short bf16x8;
typedef __attribute__((ext_vector_type(4))) float f32x4;

__device__ __forceinline__ unsigned short f2bf(float v) {
    unsigned int u = __float_as_uint(v);
    unsigned int r = (u + 0x7FFFu + ((u >> 16) & 1u)) >> 16;
    return (unsigned short)r;
}
__device__ __forceinline__ float bf2f(unsigned short h) {
    return __uint_as_float(((unsigned int)h) << 16);
}

// ---------------- split-bf16 MFMA GEMM, reg-prefetch pipelined, branch-merged ----------------
// XCD-swizzled: the nbx column-tiles sharing one A-panel run consecutively on one XCD
// so the A-panel is fetched once into that XCD's L2 (dispatch is round-robin on linear id).
// omode 0: f32 to Cf; omode 1: hi/lo bf16 to Ch/Cl; omode 2: fused 64-row max-pool.
__global__ __launch_bounds__(256, 3) void gemm_mfma(
    const unsigned short* __restrict__ Ah, const unsigned short* __restrict__ Al,
    const unsigned short* __restrict__ Wh0, const unsigned short* __restrict__ Wl0,
    const unsigned short* __restrict__ Wh1, const unsigned short* __restrict__ Wl1,
    const float* __restrict__ bias0, const float* __restrict__ bias1,
    float* __restrict__ Cf, unsigned short* __restrict__ Ch, unsigned short* __restrict__ Cl,
    int N, int Kp, int ldc, int relu, int zpad, int omode, int brshift)
{
    __shared__ __align__(16) unsigned short sAh[128][40];
    __shared__ __align__(16) unsigned short sAl[128][40];
    __shared__ __align__(16) unsigned short sBh[128][40];
    __shared__ __align__(16) unsigned short sBl[128][40];

    int tid = threadIdx.x;
    // XCD swizzle (requires gridDim.y % 8 == 0; true for all call sites: 1024, 16)
    int nbx = gridDim.x, nby = gridDim.y;
    int bid = blockIdx.y * nbx + blockIdx.x;
    int xcd = bid & 7;
    int j = bid >> 3;
    int by = xcd * (nby >> 3) + j / nbx;
    int bx = j % nbx;

    int bm = by << 7;
    int bn = bx << 7;
    int b = by >> brshift;
    const unsigned short* Wh = b ? Wh1 : Wh0;
    const unsigned short* Wl = b ? Wl1 : Wl0;
    const float* bias = b ? bias1 : bias0;

    int lane = tid & 63;
    int wid = tid >> 6;
    int wr = wid >> 1, wc = wid & 1;
    int cr = lane & 15;
    int kg = lane >> 4;

    int r0 = tid >> 2;
    int sg = (tid & 3) * 8;
    const unsigned short* pAh = Ah + (size_t)(bm + r0) * Kp + sg;
    const unsigned short* pAl = Al + (size_t)(bm + r0) * Kp + sg;
    const unsigned short* pBh = Wh + (size_t)(bn + r0) * Kp + sg;
    const unsigned short* pBl = Wl + (size_t)(bn + r0) * Kp + sg;
    size_t rstep = (size_t)64 * Kp;

    uint4 vAh0, vAh1, vAl0, vAl1, vBh0, vBh1, vBl0, vBl1;
    auto LOADT = [&](int k0) {
        vAh0 = *(const uint4*)(pAh + k0);
        vAh1 = *(const uint4*)(pAh + k0 + rstep);
        vAl0 = *(const uint4*)(pAl + k0);
        vAl1 = *(const uint4*)(pAl + k0 + rstep);
        vBh0 = *(const uint4*)(pBh + k0);
        vBh1 = *(const uint4*)(pBh + k0 + rstep);
        vBl0 = *(const uint4*)(pBl + k0);
        vBl1 = *(const uint4*)(pBl + k0 + rstep);
    };
    auto WRITET = [&]() {
        *(uint4*)&sAh[r0][sg] = vAh0;
        *(uint4*)&sAh[r0 + 64][sg] = vAh1;
        *(uint4*)&sAl[r0][sg] = vAl0;
        *(uint4*)&sAl[r0 + 64][sg] = vAl1;
        *(uint4*)&sBh[r0][sg] = vBh0;
        *(uint4*)&sBh[r0 + 64][sg] = vBh1;
        *(uint4*)&sBl[r0][sg] = vBl0;
        *(uint4*)&sBl[r0 + 64][sg] = vBl1;
    };

    f32x4 acc[4][4] = {};

    LOADT(0);
    WRITET();
    __syncthreads();

    for (int k0 = 0; k0 < Kp; k0 += 32) {
        int more = (k0 + 32) < Kp;
        if (more) LOADT(k0 + 32);

        bf16x8 bH[4], bL[4];
        #pragma unroll
        for (int nf = 0; nf < 4; ++nf) {
            bH[nf] = *(const bf16x8*)&sBh[wc * 64 + nf * 16 + cr][kg * 8];
            bL[nf] = *(const bf16x8*)&sBl[wc * 64 + nf * 16 + cr][kg * 8];
        }
        #pragma unroll
        for (int mf = 0; mf < 4; ++mf) {
            bf16x8 aH = *(const bf16x8*)&sAh[wr * 64 + mf * 16 + cr][kg * 8];
            bf16x8 aL = *(const bf16x8*)&sAl[wr * 64 + mf * 16 + cr][kg * 8];
            #pragma unroll
            for (int nf = 0; nf < 4; ++nf) {
                acc[mf][nf] = __builtin_amdgcn_mfma_f32_16x16x32_bf16(aH, bH[nf], acc[mf][nf], 0, 0, 0);
                acc[mf][nf] = __builtin_amdgcn_mfma_f32_16x16x32_bf16(aH, bL[nf], acc[mf][nf], 0, 0, 0);
                acc[mf][nf] = __builtin_amdgcn_mfma_f32_16x16x32_bf16(aL, bH[nf], acc[mf][nf], 0, 0, 0);
            }
        }
        __syncthreads();
        if (more) {
            WRITET();
            __syncthreads();
        }
    }

    if (omode == 2) {
        // fused graph max-pool: wave tile = 64 rows = one graph; g spans both branches
        int g = (by << 1) + wr;
        #pragma unroll
        for (int nf = 0; nf < 4; ++nf) {
            int col = bn + wc * 64 + nf * 16 + cr;
            if (col < N) {
                float m = -INFINITY;
                #pragma unroll
                for (int mf = 0; mf < 4; ++mf) {
                    f32x4 v = acc[mf][nf];
                    #pragma unroll
                    for (int j2 = 0; j2 < 4; ++j2) m = fmaxf(m, v[j2]);
                }
                m = fmaxf(m + bias[col], 0.f);
                m = fmaxf(m, __shfl_xor(m, 16, 64));
                m = fmaxf(m, __shfl_xor(m, 32, 64));
                if (kg == 0)
                    atomicMax((unsigned int*)&Cf[(size_t)g * ldc + col], __float_as_uint(m));
            }
        }
        return;
    }

    #pragma unroll
    for (int mf = 0; mf < 4; ++mf) {
        int rowbase = bm + wr * 64 + mf * 16 + kg * 4;
        #pragma unroll
        for (int nf = 0; nf < 4; ++nf) {
            int col = bn + wc * 64 + nf * 16 + cr;
            if (col >= ldc) continue;
            int live = col < N;
            if (!live && !zpad) continue;
            float bv = live ? bias[col] : 0.f;
            f32x4 v = acc[mf][nf];
            #pragma unroll
            for (int j2 = 0; j2 < 4; ++j2) {
                size_t idx = (size_t)(rowbase + j2) * ldc + col;
                float o = v[j2] + bv;
                if (relu) o = fmaxf(o, 0.f);
                if (!live) o = 0.f;
                if (omode == 0) {
                    Cf[idx] = o;
                } else {
                    unsigned short h = f2bf(o);
                    Ch[idx] = h;
                    Cl[idx] = f2bf(o - bf2f(h));
                }
            }
        }
    }
}

// ---------------- split-K MFMA GEMM for skinny FCs (branch-merged) ----------------
__global__ __launch_bounds__(256) void gemm_mfma_sk(
    const unsigned short* __restrict__ Ah, const unsigned short* __restrict__ Al,
    const unsigned short* __restrict__ Wh0, const unsigned short* __restrict__ Wl0,
    const unsigned short* __restrict__ Wh1, const unsigned short* __restrict__ Wl1,
    const float* __restrict__ bias0, const float* __restrict__ bias1,
    float* __restrict__ C, int Kp, int ldc, int kchunk, int brshift, int colstep)
{
    __shared__ __align__(16) unsigned short sAh[128][40];
    __shared__ __align__(16) unsigned short sAl[128][40];
    __shared__ __align__(16) unsigned short sBh[64][40];
    __shared__ __align__(16) unsigned short sBl[64][40];

    int tid = threadIdx.x;
    int bm = blockIdx.y << 7;
    int bn = blockIdx.x << 6;
    int b = blockIdx.y >> brshift;
    const unsigned short* Wh = b ? Wh1 : Wh0;
    const unsigned short* Wl = b ? Wl1 : Wl0;
    const float* bias = b ? bias1 : bias0;
    int rowoff = bm - (b << 10);
    int kbase = blockIdx.z * kchunk;
    int lane = tid & 63;
    int wid = tid >> 6;
    int wr = wid >> 1, wc = wid & 1;
    int cr = lane & 15;
    int kg = lane >> 4;

    f32x4 acc[4][2] = {};

    for (int k0 = kbase; k0 < kbase + kchunk; k0 += 32) {
        #pragma unroll
        for (int s = tid; s < 512; s += 256) {
            int r = s >> 2, seg = s & 3;
            *(uint4*)&sAh[r][seg * 8] =
                *(const uint4*)(Ah + (size_t)(bm + r) * Kp + k0 + seg * 8);
        }
        #pragma unroll
        for (int s = tid; s < 512; s += 256) {
            int r = s >> 2, seg = s & 3;
            *(uint4*)&sAl[r][seg * 8] =
                *(const uint4*)(Al + (size_t)(bm + r) * Kp + k0 + seg * 8);
        }
        {
            int r = tid >> 2, seg = tid & 3;
            *(uint4*)&sBh[r][seg * 8] =
                *(const uint4*)(Wh + (size_t)(bn + r) * Kp + k0 + seg * 8);
            *(uint4*)&sBl[r][seg * 8] =
                *(const uint4*)(Wl + (size_t)(bn + r) * Kp + k0 + seg * 8);
        }
        __syncthreads();

        bf16x8 bH[2], bL[2];
        #pragma unroll
        for (int nf = 0; nf < 2; ++nf) {
            bH[nf] = *(const bf16x8*)&sBh[wc * 32 + nf * 16 + cr][kg * 8];
            bL[nf] = *(const bf16x8*)&sBl[wc * 32 + nf * 16 + cr][kg * 8];
        }
        #pragma unroll
        for (int mf = 0; mf < 4; ++mf) {
            bf16x8 aH = *(const bf16x8*)&sAh[wr * 64 + mf * 16 + cr][kg * 8];
            bf16x8 aL = *(const bf16x8*)&sAl[wr * 64 + mf * 16 + cr][kg * 8];
            #pragma unroll
            for (int nf = 0; nf < 2; ++nf) {
                acc[mf][nf] = __builtin_amdgcn_mfma_f32_16x16x32_bf16(aH, bH[nf], acc[mf][nf], 0, 0, 0);
                acc[mf][nf] = __builtin_amdgcn_mfma_f32_16x16x32_bf16(aH, bL[nf], acc[mf][nf], 0, 0, 0);
                acc[mf][nf] = __builtin_amdgcn_mfma_f32_16x16x32_bf16(aL, bH[nf], acc[mf][nf], 0, 0, 0);
            }
        }
        __syncthreads();
    }

    int z0 = blockIdx.z == 0;
    #pragma unroll
    for (int mf = 0; mf < 4; ++mf) {
        int rowbase = rowoff + wr * 64 + mf * 16 + kg * 4;
        #pragma unroll
        for (int nf = 0; nf < 2; ++nf) {
            int cl = bn + wc * 32 + nf * 16 + cr;
            float bv = z0 ? bias[cl] : 0.f;
            int col = b * colstep + cl;
            f32x4 v = acc[mf][nf];
            #pragma unroll
            for (int j = 0; j < 4; ++j)
                atomicAdd(&C[(size_t)(rowbase + j) * ldc + col], v[j] + bv);
        }
    }
}

// ---------------- batched weight prep ----------------
struct PrepDesc { const float* W; unsigned short* Wh; unsigned short* Wl; int K, N, Kp, Np; };
struct PrepArgs { PrepDesc d[11]; };

__global__ void prep_all(PrepArgs pa) {
    PrepDesc de = pa.d[blockIdx.y];
    int tot = de.Np * de.Kp;
    for (int t = blockIdx.x * blockDim.x + threadIdx.x; t < tot; t += gridDim.x * blockDim.x) {
        int n = t / de.Kp, k = t - n * de.Kp;
        float v = (n < de.N && k < de.K) ? de.W[(size_t)k * de.N + n] : 0.f;
        unsigned short h = f2bf(v);
        de.Wh[t] = h;
        de.Wl[t] = f2bf(v - bf2f(h));
    }
}

// ---------------- f32 [M,F] -> hi/lo split, zero-padded to Kp ----------------
__global__ void split_pad(const float* __restrict__ x, unsigned short* __restrict__ Xh,
                          unsigned short* __restrict__ Xl, int M, int F, int Kp) {
    int t = blockIdx.x * blockDim.x + threadIdx.x;
    if (t >= M * Kp) return;
    int i = t / Kp, c = t - i * Kp;
    float v = (c < F) ? x[(size_t)i * F + c] : 0.f;
    unsigned short h = f2bf(v);
    Xh[t] = h;
    Xl[t] = f2bf(v - bf2f(h));
}

// ---------------- small-M FC (head only) ----------------
__global__ __launch_bounds__(256) void fc_row(
    const float* __restrict__ A, const float* __restrict__ B,
    const float* __restrict__ bias, float* __restrict__ C,
    int M, int N, int K, int lda, int ldc, int relu)
{
    int nchunks = (N + 63) >> 6;
    int bid = blockIdx.x;
    int nc = bid % nchunks;
    int m = ((bid / nchunks) << 2) + (threadIdx.x >> 6);
    int lane = threadIdx.x & 63;
    if (m >= M) return;
    int n = (nc << 6) + lane;
    int nclamp = n < N ? n : N - 1;
    const float* __restrict__ a = A + (size_t)m * lda;
    const float* __restrict__ bp = B + nclamp;
    float acc = 0.f;
    int kk = 0;
    #pragma unroll 4
    for (; kk + 4 <= K; kk += 4) {
        float a0 = a[kk + 0], a1 = a[kk + 1], a2 = a[kk + 2], a3 = a[kk + 3];
        float b0 = bp[(size_t)(kk + 0) * N];
        float b1 = bp[(size_t)(kk + 1) * N];
        float b2 = bp[(size_t)(kk + 2) * N];
        float b3 = bp[(size_t)(kk + 3) * N];
        acc = fmaf(a0, b0, acc);
        acc = fmaf(a1, b1, acc);
        acc = fmaf(a2, b2, acc);
        acc = fmaf(a3, b3, acc);
    }
    for (; kk < K; ++kk)
        acc = fmaf(a[kk], bp[(size_t)kk * N], acc);
    if (n < N) {
        float v = acc + bias[n];
        if (relu) v = fmaxf(v, 0.f);
        C[(size_t)m * ldc + n] = v;
    }
}

// ---------------- bucketed CSR build (two-level scatter) ----------------
__global__ __launch_bounds__(1024) void bucket_scatter(
    const int* __restrict__ s1, const int* __restrict__ d1,
    const int* __restrict__ s2, const int* __restrict__ d2,
    int* __restrict__ bcnt, unsigned int* __restrict__ bbuf, int E)
{
    __shared__ int lhist[256];
    __shared__ int lbase[256];
    int nblk = E / EPB;
    int b = blockIdx.x >= nblk;
    int blk = blockIdx.x - b * nblk;
    const int* sp = b ? s2 : s1;
    const int* dp = b ? d2 : d1;
    int e0 = blk * EPB;
    if (threadIdx.x < 256) lhist[threadIdx.x] = 0;
    __syncthreads();

    unsigned int pack[EPB / 1024];
    int bkt[EPB / 1024], rank[EPB / 1024];
    #pragma unroll
    for (int i = 0; i < EPB / 1024; ++i) {
        int e = e0 + threadIdx.x + i * 1024;
        int s = sp[e], d = dp[e];
        bkt[i] = d >> 8;
        pack[i] = ((unsigned int)s << 8) | (unsigned int)(d & 255);
        rank[i] = atomicAdd(&lhist[bkt[i]], 1);
    }
    __syncthreads();
    if (threadIdx.x < 256) {
        int c = lhist[threadIdx.x];
        lbase[threadIdx.x] = c ? atomicAdd(&bcnt[(b << 8) | threadIdx.x], c) : 0;
    }
    __syncthreads();
    #pragma unroll
    for (int i = 0; i < EPB / 1024; ++i) {
        int pos = lbase[bkt[i]] + rank[i];
        if (pos < BCAP)
            bbuf[(size_t)((b << 8) | bkt[i]) * BCAP + pos] = pack[i];
    }
}

__global__ __launch_bounds__(256) void bucket_count(const int* __restrict__ bcnt,
                                                    const unsigned int* __restrict__ bbuf,
                                                    int* __restrict__ cntB) {
    __shared__ int lc[256];
    int bk = blockIdx.x;
    lc[threadIdx.x] = 0;
    __syncthreads();
    int n = bcnt[bk]; if (n > BCAP) n = BCAP;
    const unsigned int* p = bbuf + (size_t)bk * BCAP;
    for (int i = threadIdx.x; i < n; i += 256)
        atomicAdd(&lc[p[i] & 255u], 1);
    __syncthreads();
    int br = bk >> 8, nb = (bk & 255) << 8;
    cntB[br * N_NODES + nb + threadIdx.x] = lc[threadIdx.x];
}

// Pass B2: counting sort -> CSR slab; entry = (src << 16) | deg(src)
// (src < 65536 fits 16 bits; deg(src) from cntB, so gather can recompute
//  dinv[src] = rsqrtf(deg+1) bit-identically without a random dinv load)
__global__ __launch_bounds__(256) void bucket_sort(const int* __restrict__ bcnt,
                                                   const unsigned int* __restrict__ bbuf,
                                                   const int* __restrict__ rowpB,
                                                   const int* __restrict__ cntB,
                                                   unsigned int* __restrict__ csrsB) {
    __shared__ int lrow[256];
    __shared__ int lcur[256];
    int bk = blockIdx.x;
    int br = bk >> 8, nb = (bk & 255) << 8;
    lrow[threadIdx.x] = rowpB[br * RPS + nb + threadIdx.x];
    lcur[threadIdx.x] = 0;
    __syncthreads();
    int n = bcnt[bk]; if (n > BCAP) n = BCAP;
    const unsigned int* p = bbuf + (size_t)bk * BCAP;
    unsigned int* outp = csrsB + (size_t)br * N_EDGES;
    const int* cnt = cntB + br * N_NODES;
    for (int i = threadIdx.x; i < n; i += 256) {
        unsigned int e = p[i];
        int dl = e & 255u;
        int s = (int)(e >> 8);
        int pos = lrow[dl] + atomicAdd(&lcur[dl], 1);
        outp[pos] = ((unsigned int)s << 16) | (unsigned int)(cnt[s] & 0xFFFF);
    }
}

__global__ void make_dinv2(const int* __restrict__ cnt, float* __restrict__ dinv) {
    int t = blockIdx.x * blockDim.x + threadIdx.x;
    if (t < 2 * N_NODES) dinv[t] = rsqrtf((float)cnt[t] + 1.0f);
}

__global__ __launch_bounds__(1024) void scan_rowptr(const int* __restrict__ cntB,
                                                    int* __restrict__ rowpB) {
    __shared__ int sums[1024];
    const int* cnt = cntB + blockIdx.x * N_NODES;
    int* row_ptr = rowpB + blockIdx.x * RPS;
    int t = threadIdx.x;
    int base = t * 64;
    int s = 0;
    #pragma unroll 4
    for (int i = 0; i < 64; ++i) s += cnt[base + i];
    sums[t] = s;
    __syncthreads();
    for (int off = 1; off < 1024; off <<= 1) {
        int v = sums[t];
        int add = (t >= off) ? sums[t - off] : 0;
        __syncthreads();
        sums[t] = v + add;
        __syncthreads();
    }
    int run = (t == 0) ? 0 : sums[t - 1];
    for (int i = 0; i < 64; ++i) {
        row_ptr[base + i] = run;
        run += cnt[base + i];
    }
    if (t == 1023) row_ptr[N_NODES] = run;
}

// pad-repack both branches: x1/x2 [65536,78] -> xp [131072,80]
__global__ void repack_pad2(const float* __restrict__ x1, const float* __restrict__ x2,
                            float* __restrict__ xp) {
    int t = blockIdx.x * blockDim.x + threadIdx.x;
    int total = 2 * N_NODES * 80;
    if (t >= total) return;
    int i = t / 80, c = t - i * 80;
    int b = i >> 16, il = i & 65535;
    const float* x = b ? x2 : x1;
    xp[t] = (c < FD) ? x[(size_t)il * FD + c] : 0.f;
}

// gather + normalize + split, both branches; 8 features/thread, edge loop x4.
// CSR entry = (src<<16)|deg: dinv[src] recomputed via rsqrtf (bit-identical),
// removing the random per-edge dinv load from the dependent chain.
__global__ __launch_bounds__(256) void gather8(
    const float* __restrict__ x, const int* __restrict__ rowpB,
    const unsigned int* __restrict__ csrsB, const float* __restrict__ dinvB,
    unsigned short* __restrict__ Ah, unsigned short* __restrict__ Al,
    int S, int Kp)
{
    int Kp8 = Kp >> 3;
    int t = blockIdx.x * blockDim.x + threadIdx.x;
    int total = 2 * N_NODES * Kp8;
    if (t >= total) return;
    int i = t / Kp8;                 // global row 0..131071
    int g = t - i * Kp8;
    int f = g << 3;
    size_t ob = (size_t)i * Kp + f;
    if (f >= S) {
        bf16x8 z = {};
        *(bf16x8*)&Ah[ob] = z;
        *(bf16x8*)&Al[ob] = z;
        return;
    }
    int b = i >> 16, il = i & 65535;
    const int* rowp = rowpB + b * RPS;
    const unsigned int* csrs = csrsB + (size_t)b * N_EDGES;
    const float* dinv = dinvB + ((size_t)b << 16);
    const float* xb = x + (((size_t)b << 16) * S);
    float di = dinv[il];
    const float* xr = x + (size_t)i * S + f;
    f32x4 s0 = *(const f32x4*)xr;
    f32x4 s1 = *(const f32x4*)(xr + 4);
    float w = di * di;
    s0 *= w;
    s1 *= w;
    int p0 = rowp[il], p1 = rowp[il + 1];
    int p = p0;
    for (; p + 4 <= p1; p += 4) {
        unsigned int ea = csrs[p], eb = csrs[p + 1], ec = csrs[p + 2], ed = csrs[p + 3];
        int sa = ea >> 16, sb = eb >> 16, sc = ec >> 16, sd = ed >> 16;
        float ca = rsqrtf((float)(ea & 0xFFFFu) + 1.0f) * di;
        float cb = rsqrtf((float)(eb & 0xFFFFu) + 1.0f) * di;
        float cc = rsqrtf((float)(ec & 0xFFFFu) + 1.0f) * di;
        float cd = rsqrtf((float)(ed & 0xFFFFu) + 1.0f) * di;
        const float* ra = xb + (size_t)sa * S + f;
        const float* rb = xb + (size_t)sb * S + f;
        const float* rc = xb + (size_t)sc * S + f;
        const float* rd = xb + (size_t)sd * S + f;
        f32x4 a0 = *(const f32x4*)ra, a1 = *(const f32x4*)(ra + 4);
        f32x4 b0 = *(const f32x4*)rb, b1 = *(const f32x4*)(rb + 4);
        f32x4 c0 = *(const f32x4*)rc, c1 = *(const f32x4*)(rc + 4);
        f32x4 d0 = *(const f32x4*)rd, d1 = *(const f32x4*)(rd + 4);
        s0 += ca * a0 + cb * b0 + cc * c0 + cd * d0;
        s1 += ca * a1 + cb * b1 + cc * c1 + cd * d1;
    }
    for (; p < p1; ++p) {
        unsigned int ea = csrs[p];
        int sa = ea >> 16;
        float ca = rsqrtf((float)(ea & 0xFFFFu) + 1.0f) * di;
        const float* ra = xb + (size_t)sa * S + f;
        s0 += ca * *(const f32x4*)ra;
        s1 += ca * *(const f32x4*)(ra + 4);
    }
    bf16x8 hh, ll;
    #pragma unroll
    for (int j = 0; j < 4; ++j) {
        unsigned short h0 = f2bf(s0[j]);
        hh[j] = (short)h0;
        ll[j] = (short)f2bf(s0[j] - bf2f(h0));
        unsigned short h1 = f2bf(s1[j]);
        hh[4 + j] = (short)h1;
        ll[4 + j] = (short)f2bf(s1[j] - bf2f(h1));
    }
    *(bf16x8*)&Ah[ob] = hh;
    *(bf16x8*)&Al[ob] = ll;
}

// ---------------- host side ----------------
static inline void fc_launch(const float* A, const float* B, const float* bias, float* C,
                             int M, int N, int K, int lda, int ldc, int relu, hipStream_t s) {
    int nchunks = (N + 63) / 64;
    int mblocks = (M + 3) / 4;
    fc_row<<<nchunks * mblocks, 256, 0, s>>>(A, B, bias, C, M, N, K, lda, ldc, relu);
}

extern "C" void kernel_launch(void* const* d_in, const int* in_sizes, int n_in,
                              void* d_out, int out_size, void* d_ws, size_t ws_size,
                              hipStream_t stream) {
    (void)in_sizes; (void)n_in; (void)out_size; (void)ws_size;

    const float* x1     = (const float*)d_in[0];
    const int*   ei1    = (const int*)d_in[1];
    const float* x2     = (const float*)d_in[3];
    const int*   ei2    = (const int*)d_in[4];
    const float* target = (const float*)d_in[6];

    const float* xt_w  = (const float*)d_in[27];
    const float* xt_b  = (const float*)d_in[28];
    const float* fc1_w = (const float*)d_in[29];
    const float* fc1_b = (const float*)d_in[30];
    const float* fc2_w = (const float*)d_in[31];
    const float* fc2_b = (const float*)d_in[32];
    const float* out_w = (const float*)d_in[33];
    const float* out_b = (const float*)d_in[34];

    char* ws = (char*)d_ws;
    // merged-branch layout (total 180,224,512 B)
    unsigned short* AhB = (unsigned short*)(ws + 0);           // 41,943,040 (131072 x 160 max)
    unsigned short* AlB = (unsigned short*)(ws + 41943040);    // 41,943,040
    float* R1   = (float*)(ws + 83886080);     // xpad/y1 [131072][80]
    float* Y2   = (float*)(ws + 83886080);     // y2 [131072][160] (overlays R1 after y1 dead)
    char*  FCS  = ws + 83886080;               // fc scratch (after y2 dead)
    unsigned int* csrsB = (unsigned int*)(ws + 167772160);   // 4,194,304
    int*   rowpB = (int*) (ws + 171966464);    // 524,800
    int*   cntB  = (int*) (ws + 172491264);    // 524,288
    float* dinvB = (float*)(ws + 173015552);   // 524,288
    float* xc   = (float*)(ws + 173539840);    // 1,048,576
    float* xc1  = (float*)(ws + 174588416);    // 524,288
    float* xc2  = (float*)(ws + 175112704);    // 131,072
    unsigned short* wt    = (unsigned short*)(ws + 175243776); // 786,432
    unsigned short* wtfc1 = (unsigned short*)(ws + 176030208); // 2,621,440
    unsigned short* wtfc2 = (unsigned short*)(ws + 178651648); // 1,048,576
    unsigned short* wtxt  = (unsigned short*)(ws + 179700224); // 524,288

    // CSR-build scratch aliases AhB/AlB (dead until convs)
    unsigned int* bbuf = (unsigned int*)AhB;   // 6,291,456
    int*          bcnt = (int*)AlB;            // 2,048

    float* xpad = R1;
    float* y1   = R1;
    float* y2   = Y2;
    // fc scratch (alias y2 region; only used after gather3 consumed y2)
    float*          pooled = (float*)(FCS + 0);          // 2048x320 f32 = 2,621,440
    unsigned short* Ph = (unsigned short*)(FCS + 2621440);   // 1,310,720
    unsigned short* Pl = (unsigned short*)(FCS + 3932160);   // 1,310,720
    unsigned short* Fh = (unsigned short*)(FCS + 5242880);   // 4,194,304
    unsigned short* Fl = (unsigned short*)(FCS + 9437184);   // 4,194,304
    unsigned short* Th = (unsigned short*)(FCS + 13631488);  // 2,097,152
    unsigned short* Tl = (unsigned short*)(FCS + 15728640);  // 2,097,152

    const int E = N_EDGES;

    const int Ks[3]  = { FD, FD, FD * 2 };
    const int Ns[3]  = { FD, FD * 2, FD * 4 };
    const int Kps[3] = { 96, 96, 160 };
    const int Nps[3] = { 128, 256, 384 };
    const int Ss[3]  = { 80, 80, 160 };
    const int Ldc[3] = { 80, 160, 320 };      // conv3 ldc = pooled stride 320
    const int wtoff[3] = { 0, 24576, 73728 };
    const int WT_BRANCH = 196608;

    // ---- batched weight prep (1 launch) ----
    PrepArgs pa;
    for (int br = 0; br < 2; ++br) {
        int base = 7 + br * 10;
        for (int c = 0; c < 3; ++c) {
            unsigned short* wh = wt + br * WT_BRANCH + wtoff[c];
            pa.d[br * 3 + c] = { (const float*)d_in[base + 2 * c], wh,
                                 wh + Nps[c] * Kps[c], Ks[c], Ns[c], Kps[c], Nps[c] };
        }
        pa.d[6 + br] = { (const float*)d_in[base + 6], wtfc1 + br * 655360,
                         wtfc1 + br * 655360 + 327680, FD * 4, 1024, 320, 1024 };
        pa.d[8 + br] = { (const float*)d_in[base + 8], wtfc2 + br * 262144,
                         wtfc2 + br * 262144 + 131072, 1024, 64, 1024, 128 };
    }
    pa.d[10] = { xt_w, wtxt, wtxt + 131072, 1000, 128, 1024, 128 };
    prep_all<<<dim3(256, 11), 256, 0, stream>>>(pa);

    // ---- bucketed CSR build, both branches ----
    const int* src1 = ei1, *dst1 = ei1 + E;
    const int* src2 = ei2, *dst2 = ei2 + E;
    hipMemsetAsync(bcnt, 0, 512 * sizeof(int), stream);
    bucket_scatter<<<2 * (E / EPB), 1024, 0, stream>>>(src1, dst1, src2, dst2, bcnt, bbuf, E);
    bucket_count<<<512, 256, 0, stream>>>(bcnt, bbuf, cntB);
    make_dinv2<<<(2 * N_NODES + 255) / 256, 256, 0, stream>>>(cntB, dinvB);
    scan_rowptr<<<2, 1024, 0, stream>>>(cntB, rowpB);
    bucket_sort<<<512, 256, 0, stream>>>(bcnt, bbuf, rowpB, cntB, csrsB);

    hipMemsetAsync(xc, 0, N_GRAPHS * 256 * sizeof(float), stream);

    // ---- merged conv chain (both branches per dispatch) ----
    repack_pad2<<<(2 * N_NODES * 80 + 255) / 256, 256, 0, stream>>>(x1, x2, xpad);

    const float* cin[3]  = { xpad, y1, y2 };
    float*       cout[3] = { y1, y2, pooled };
    const float* biasc[2][3];
    for (int br = 0; br < 2; ++br) {
        int base = 7 + br * 10;
        biasc[br][0] = (const float*)d_in[base + 1];
        biasc[br][1] = (const float*)d_in[base + 3];
        biasc[br][2] = (const float*)d_in[base + 5];
    }

    for (int c = 0; c < 3; ++c) {
        int Kp = Kps[c], Np = Nps[c], S = Ss[c];
        int total = 2 * N_NODES * (Kp >> 3);
        gather8<<<(total + 255) / 256, 256, 0, stream>>>(
            cin[c], rowpB, csrsB, dinvB, AhB, AlB, S, Kp);
        unsigned short* wh0 = wt + wtoff[c];
        unsigned short* wh1 = wt + WT_BRANCH + wtoff[c];
        if (c == 2) {
            hipMemsetAsync(pooled, 0, 2048 * 320 * sizeof(float), stream);
            gemm_mfma<<<dim3(Np / 128, 1024), 256, 0, stream>>>(
                AhB, AlB, wh0, wh0 + Np * Kp, wh1, wh1 + Np * Kp,
                biasc[0][2], biasc[1][2],
                pooled, nullptr, nullptr, Ns[c], Kp, 320, 1, 0, 2, 9);
        } else {
            gemm_mfma<<<dim3(Np / 128, 1024), 256, 0, stream>>>(
                AhB, AlB, wh0, wh0 + Np * Kp, wh1, wh1 + Np * Kp,
                biasc[0][c], biasc[1][c],
                cout[c], nullptr, nullptr, Ns[c], Kp, Ldc[c], 1, 1, 0, 9);
        }
    }

    // ---- merged branch MLP ----
    split_pad<<<(2048 * 320 + 255) / 256, 256, 0, stream>>>(pooled, Ph, Pl, 2048, 320, 320);
    gemm_mfma<<<dim3(8, 16), 256, 0, stream>>>(
        Ph, Pl, wtfc1, wtfc1 + 327680, wtfc1 + 655360, wtfc1 + 655360 + 327680,
        (const float*)d_in[7 + 7], (const float*)d_in[17 + 7],
        nullptr, Fh, Fl, 1024, 320, 1024, 1, 1, 1, 3);
    gemm_mfma_sk<<<dim3(1, 16, 8), 256, 0, stream>>>(
        Fh, Fl, wtfc2, wtfc2 + 131072, wtfc2 + 262144, wtfc2 + 262144 + 131072,
        (const float*)d_in[7 + 9], (const float*)d_in[17 + 9],
        xc, 1024, 256, 128, 3, 64);

    // xt: split target, split-K -> xc cols [128,256)
    split_pad<<<(1024 * 1024 + 255) / 256, 256, 0, stream>>>(target, Th, Tl, 1024, 1000, 1024);
    gemm_mfma_sk<<<dim3(2, 8, 8), 256, 0, stream>>>(
        Th, Tl, wtxt, wtxt + 131072, wtxt, wtxt + 131072, xt_b, xt_b,
        xc + 128, 1024, 256, 128, 30, 0);

    // head
    fc_launch(xc,  fc1_w, fc1_b, xc1, N_GRAPHS, 128, 256, 256, 128, 1, stream);
    fc_launch(xc1, fc2_w, fc2_b, xc2, N_GRAPHS, 32, 128, 128, 32, 1, stream);
    fc_launch(xc2, out_w, out_b, (float*)d_out, N_GRAPHS, 1, 32, 32, 1, 0, stream);
}